// Round 6
// baseline (6544.569 us; speedup 1.0000x reference)
//
#include <hip/hip_runtime.h>
#include <cstdio>
#include <cstdint>

typedef unsigned short u16;
typedef unsigned int u32;
typedef float f32x4 __attribute__((ext_vector_type(4)));
typedef short s16x8 __attribute__((ext_vector_type(8)));
typedef int i32x4 __attribute__((ext_vector_type(4)));

#define DI __device__ __forceinline__

// problem sizes
#define BATCH 32
#define SEQT 512
#define HDIM 1024
#define PDIM 512
#define DEMB 512
#define G4H 4096
#define NWGR 256  // workgroups in the persistent recurrence kernel

// ---------------- bf16 helpers (RNE + hi/lo split) ----------------
DI u16 f2bf(float f) {
  u32 u = __float_as_uint(f);
  return (u16)((u + 0x7fffu + ((u >> 16) & 1u)) >> 16);
}
DI float bf2f(u16 h) { return __uint_as_float(((u32)h) << 16); }
DI void split2(float f, u16 &hi, u16 &lo) {
  hi = f2bf(f);
  lo = f2bf(f - bf2f(hi));  // exact residual capture to ~2^-17 rel
}
DI f32x4 mfma16(s16x8 a, s16x8 b, f32x4 c) {
  return __builtin_amdgcn_mfma_f32_16x16x32_bf16(a, b, c, 0, 0, 0);
}
DI void dma16(const void *g, void *l) {
  __builtin_amdgcn_global_load_lds((const __attribute__((address_space(1))) void *)g,
                                   (__attribute__((address_space(3))) void *)l, 16, 0, 0);
}
// device-scope (sc1) stores: write-through to the coherence point (L3).
// No buffer_inv / buffer_wbl2 needed anywhere in the recurrence handshake.
// NOTE: payload must be a native ext_vector type — clang can't map the HIP
// struct int4 to a VGPR tuple in asm constraints (R5 build break).
DI void st128_dev(u16 *p, i32x4 v) {
  asm volatile("global_store_dwordx4 %0, %1, off sc1" ::"v"(p), "v"(v) : "memory");
}
DI void st32_dev(int *p, int v) {
  asm volatile("global_store_dword %0, %1, off sc1" ::"v"(p), "v"(v) : "memory");
}

// fast gate math: hardware exp2 + rcp (~1e-7 abs err on sigmoid/tanh outputs)
#if __has_builtin(__builtin_amdgcn_exp2f) && __has_builtin(__builtin_amdgcn_rcpf)
DI float fsig(float x) {
  return __builtin_amdgcn_rcpf(1.f + __builtin_amdgcn_exp2f(-1.4426950408889634f * x));
}
DI float ftanh(float x) {
  return 2.f * __builtin_amdgcn_rcpf(1.f + __builtin_amdgcn_exp2f(-2.8853900817779268f * x)) - 1.f;
}
#else
DI float fsig(float x) { return 1.f / (1.f + expf(-x)); }
DI float ftanh(float x) { return tanhf(x); }
#endif

// ---------------- embed gather -> x0 hi/lo planes ----------------
__global__ void k_gather_pack(const int *__restrict__ tokens, const float *__restrict__ embed,
                              u16 *__restrict__ xhi, u16 *__restrict__ xlo) {
  int idx = blockIdx.x * 256 + threadIdx.x;  // one thread per 8 elements
  int m = idx >> 6;                          // row 0..16383 (m = b*T + t)
  int k8 = (idx & 63) << 3;
  int tok = tokens[m];
  const float *src = embed + (size_t)tok * DEMB + k8;
  float4 a = *(const float4 *)src;
  float4 b = *(const float4 *)(src + 4);
  float v[8] = {a.x, a.y, a.z, a.w, b.x, b.y, b.z, b.w};
  union UV { u16 h[8]; int4 v; };
  UV uh, ul;
#pragma unroll
  for (int j = 0; j < 8; ++j) split2(v[j], uh.h[j], ul.h[j]);
  size_t o = (size_t)m * DEMB + k8;
  *(int4 *)(xhi + o) = uh.v;
  *(int4 *)(xlo + o) = ul.v;
}

// ------- transpose+split weights: W[K][N] f32 -> T[N][K] bf16 hi/lo -------
__global__ void k_packT(const float *__restrict__ W, u16 *__restrict__ Thi, u16 *__restrict__ Tlo,
                        int K, int N) {
  __shared__ float tile[32][33];
  int n0 = blockIdx.x * 32, k0 = blockIdx.y * 32;
  int tx = threadIdx.x, ty = threadIdx.y;  // (32,8)
#pragma unroll
  for (int i = 0; i < 4; ++i) tile[ty + 8 * i][tx] = W[(size_t)(k0 + ty + 8 * i) * N + n0 + tx];
  __syncthreads();
#pragma unroll
  for (int i = 0; i < 4; ++i) {
    int n = ty + 8 * i;
    u16 hi, lo;
    split2(tile[tx][n], hi, lo);
    size_t o = (size_t)(n0 + n) * K + k0 + tx;
    Thi[o] = hi;
    Tlo[o] = lo;
  }
}

// ---------------- generic bf16x3 GEMM ----------------
// C[M][N] = A[M][K] * B^T-source[N][K] + bias, A/B given as bf16 hi/lo planes.
// 128x128 tile, BK=64, 4 waves. Both tiles DMA-staged via global_load_lds(16)
// into XOR-swizzled LDS (swizzle folded into per-lane SOURCE address).
// OM: 0 = bf16 out, 1 = hi/lo split out, 2 = f32 out scattered to (B,T,P).
template <int OM>
__global__ __launch_bounds__(256, 2) void k_gemm(const u16 *__restrict__ Ahi, const u16 *__restrict__ Alo,
                                                 const u16 *__restrict__ Bhi, const u16 *__restrict__ Blo,
                                                 const float *__restrict__ bias, void *__restrict__ out0,
                                                 void *__restrict__ out1, int M, int N, int K) {
  __shared__ u16 sP[4][128 * 64];  // planes: Ahi, Alo, Bhi, Blo (16KB each)
  const int tid = threadIdx.x;
  const int w = tid >> 6, lane = tid & 63;
  const int la15 = lane & 15, la4 = lane >> 4;
  const int nbn = N >> 7;
  const int bm = blockIdx.x / nbn, bn = blockIdx.x % nbn;
  const u16 *src = (w == 0) ? Ahi : (w == 1) ? Alo : (w == 2) ? Bhi : Blo;
  const int rowbase = (w < 2) ? bm * 128 : bn * 128;
  char *lds = (char *)&sP[w][0];

  f32x4 acc[2][8] = {};
  for (int kb = 0; kb < K; kb += 64) {
#pragma unroll
    for (int i = 0; i < 16; ++i) {
      int s = i * 64 + lane;            // 16B slot id
      int row = s >> 3;                 // 8 slots per 128B row
      int k16 = (s & 7) ^ (row & 7);    // inverse of read swizzle
      dma16(src + (size_t)(rowbase + row) * K + kb + k16 * 8, lds + i * 1024);
    }
    asm volatile("s_waitcnt vmcnt(0)" ::: "memory");
    __syncthreads();
#pragma unroll
    for (int ksl = 0; ksl < 2; ++ksl) {
      s16x8 ah[2], al[2];
#pragma unroll
      for (int rf = 0; rf < 2; ++rf) {
        int row = 32 * w + 16 * rf + la15;
        int slot = row * 8 + ((4 * ksl + la4) ^ (row & 7));
        ah[rf] = *(const s16x8 *)((const char *)&sP[0][0] + slot * 16);
        al[rf] = *(const s16x8 *)((const char *)&sP[1][0] + slot * 16);
      }
#pragma unroll
      for (int cf = 0; cf < 8; ++cf) {
        int col = 16 * cf + la15;
        int slot = col * 8 + ((4 * ksl + la4) ^ (col & 7));
        s16x8 bh = *(const s16x8 *)((const char *)&sP[2][0] + slot * 16);
        s16x8 bl = *(const s16x8 *)((const char *)&sP[3][0] + slot * 16);
#pragma unroll
        for (int rf = 0; rf < 2; ++rf) {
          acc[rf][cf] = mfma16(ah[rf], bh, acc[rf][cf]);
          acc[rf][cf] = mfma16(ah[rf], bl, acc[rf][cf]);
          acc[rf][cf] = mfma16(al[rf], bh, acc[rf][cf]);
        }
      }
    }
    __syncthreads();
  }
  // epilogue: D[r][c], r = 4*(lane>>4)+q (M), c = lane&15 (N)  [m89-verified]
#pragma unroll
  for (int rf = 0; rf < 2; ++rf) {
#pragma unroll
    for (int cf = 0; cf < 8; ++cf) {
      int c = bn * 128 + 16 * cf + la15;
      float bv = bias ? bias[c] : 0.f;
#pragma unroll
      for (int q = 0; q < 4; ++q) {
        int r = bm * 128 + 32 * w + 16 * rf + 4 * la4 + q;
        float v = acc[rf][cf][q] + bv;
        if (OM == 0) {
          ((u16 *)out0)[(size_t)r * N + c] = f2bf(v);
        } else if (OM == 1) {
          u16 hi, lo;
          split2(v, hi, lo);
          ((u16 *)out0)[(size_t)r * N + c] = hi;
          ((u16 *)out1)[(size_t)r * N + c] = lo;
        } else {
          int b2 = r & 31, tt = r >> 5;  // A rows are m = t*32 + b
          ((float *)out0)[((size_t)b2 * SEQT + tt) * PDIM + c] = v;
        }
      }
    }
  }
}

// ---------------- persistent LSTM recurrence ----------------
// 256 WGs x 256 threads, 1 WG/CU.
// R5 WG mapping (XCD-aware): xcd = wg&7, idx = wg>>3; rg = xcd&1 (16 batch
// rows), g = (xcd>>1)*32 + idx (8 h-cols). Each XCD serves one rg-half and a
// contiguous g-range -> xz lines and hist[t-1] lines are shared in its L2.
// R5 handshake (zero cache-maintenance, L2-assisted broadcast):
//  producer: gate threads stage h hi/lo in LDS; wave0 issues 32 packed
//            global_store_dwordx4 sc1 (write-through to L3, nothing dirty),
//            s_waitcnt vmcnt(0), then ONE sc1 flag store (monotonic t+1).
//            All ordering is single-wave program order.
//  consumer: wave0 polls the 128 flags of its rg half (atomic, bypasses
//            L2) -> __syncthreads -> all waves read h[t-1] with NORMAL cached
//            loads from the write-once hist region. Safe: lines of step t-1
//            are demand-filled only after flag t-1 (never cached pre-write,
//            never dirty anywhere, step regions line-disjoint).
__global__ __launch_bounds__(256, 1) void k_recur(const u16 *__restrict__ xz, const float *__restrict__ Wh,
                                                  u16 *hist_hi, u16 *hist_lo, int *flags, int rowmode) {
  __shared__ u16 sW[2][32 * 1024];   // 128 KiB: [zc][k] u16, swizzled
  __shared__ float zacc[4][16][33];  // per-wave K-partials (+1 col pad)
  __shared__ float sC[128];          // cell state c[16 rows][8 cols]
  __shared__ __align__(16) u16 sH[2][16][8];  // h hi/lo staging (16B rows)
  const int tid = threadIdx.x;
  const int w = tid >> 6, lane = tid & 63;
  const int la15 = lane & 15, la4 = lane >> 4;
  const int wg = blockIdx.x;
  const int xcd = wg & 7, idx = wg >> 3;
  const int rg = xcd & 1;
  const int g = (xcd >> 1) * 32 + idx;

  // stage Wh column-slice, split hi/lo, swizzled (once per launch)
  for (int i2 = tid; i2 < 32 * 1024; i2 += 256) {
    int zc = i2 & 31;
    int k = i2 >> 5;
    int gate = zc >> 3, cl = zc & 7;
    int gcol = gate * HDIM + 8 * g + cl;
    u16 hi, lo;
    split2(Wh[(size_t)k * G4H + gcol], hi, lo);
    int boff = zc * 2048 + ((((k >> 3) ^ (zc & 7))) << 4) + (k & 7) * 2;
    *(u16 *)((char *)&sW[0][0] + boff) = hi;
    *(u16 *)((char *)&sW[1][0] + boff) = lo;
  }
  if (tid < 128) sC[tid] = 0.f;
  __syncthreads();

  const int r_g = tid >> 3, hc = tid & 7;  // gate-phase coords (tid<128)
  const int bg = 16 * rg + r_g;
  const int ks0 = 8 * w;         // this wave's k-slice range
  const int bA = 16 * rg + la15; // A-operand batch row

  for (int t = 0; t < SEQT; ++t) {
    // prefetch xz for this step (normal loads; latency hidden under the poll)
    float xzv[4] = {0.f, 0.f, 0.f, 0.f};
    if (tid < 128) {
      size_t m = (rowmode == 0) ? ((size_t)bg * SEQT + t) : ((size_t)t * 32 + bg);
      const u16 *px = xz + m * G4H + 8 * g + hc;
#pragma unroll
      for (int gi = 0; gi < 4; ++gi) xzv[gi] = bf2f(px[(size_t)gi * HDIM]);
    }
    if (t > 0 && w == 0) {
      // wave0 polls the 128 producer flags of its rg half (monotonic >= t)
      const int *dp = flags + rg * 128 + lane;
      for (long tries = 0;; ++tries) {
        int a = __hip_atomic_load(dp, __ATOMIC_RELAXED, __HIP_MEMORY_SCOPE_AGENT);
        int b = __hip_atomic_load(dp + 64, __ATOMIC_RELAXED, __HIP_MEMORY_SCOPE_AGENT);
        if (__all(a >= t && b >= t)) break;
        if (tries > (1L << 22)) break;  // safety valve, never hit when co-resident
        __builtin_amdgcn_s_sleep(1);
      }
    }
    __syncthreads();  // hist step-(t-1) region valid once wave0's poll hit
    if (t > 0) {
      // z-slice partial: A = h[t-1] hist rows (NORMAL cached loads), B = sW
      const u16 *ph = hist_hi + ((size_t)(t - 1) * 32 + bA) * HDIM;
      const u16 *pl = hist_lo + ((size_t)(t - 1) * 32 + bA) * HDIM;
      s16x8 ahi[8], alo[8];
#pragma unroll
      for (int j8 = 0; j8 < 8; ++j8) {
        int k = 32 * (ks0 + j8) + 8 * la4;
        ahi[j8] = *(const s16x8 *)(ph + k);
        alo[j8] = *(const s16x8 *)(pl + k);
      }
      f32x4 acc[2] = {};
#pragma unroll
      for (int j8 = 0; j8 < 8; ++j8) {
#pragma unroll
        for (int cf = 0; cf < 2; ++cf) {
          int zc = 16 * cf + la15;
          int slot = (4 * (ks0 + j8) + la4) ^ (zc & 7);
          int boff = zc * 2048 + (slot << 4);
          s16x8 bh = *(const s16x8 *)((const char *)&sW[0][0] + boff);
          s16x8 bl = *(const s16x8 *)((const char *)&sW[1][0] + boff);
          acc[cf] = mfma16(ahi[j8], bh, acc[cf]);
          acc[cf] = mfma16(ahi[j8], bl, acc[cf]);
          acc[cf] = mfma16(alo[j8], bh, acc[cf]);
        }
      }
#pragma unroll
      for (int cf = 0; cf < 2; ++cf)
#pragma unroll
        for (int q = 0; q < 4; ++q) zacc[w][4 * la4 + q][16 * cf + la15] = acc[cf][q];
    }
    __syncthreads();
    if (tid < 128) {
      float z4[4];
#pragma unroll
      for (int gi = 0; gi < 4; ++gi) {
        float s = xzv[gi];
        if (t > 0) {
          int zc = gi * 8 + hc;
          s += zacc[0][r_g][zc] + zacc[1][r_g][zc] + zacc[2][r_g][zc] + zacc[3][r_g][zc];
        }
        z4[gi] = s;
      }
      float ig = fsig(z4[0]);
      float fg = fsig(z4[1]);
      float gg = ftanh(z4[2]);
      float og = fsig(z4[3]);
      float c = fg * sC[tid] + ig * gg;
      sC[tid] = c;
      float h = og * ftanh(c);
      u16 hi, lo;
      split2(h, hi, lo);
      sH[0][r_g][hc] = hi;
      sH[1][r_g][hc] = lo;
    }
    __syncthreads();  // sH complete
    // wave0: packed 16B sc1 stores (write-through), drain, then flag.
    if (tid < 32) {
      int p = tid >> 4, r = tid & 15;
      i32x4 v = *(const i32x4 *)&sH[p][r][0];
      u16 *base = p ? hist_lo : hist_hi;
      st128_dev(base + ((size_t)t * 32 + 16 * rg + r) * HDIM + 8 * g, v);
    }
    if (w == 0) {
      asm volatile("s_waitcnt vmcnt(0)" ::: "memory");  // wave0's stores at L3
      if (tid == 0) st32_dev(flags + rg * 128 + g, t + 1);
    }
  }
}

// ---------------- host launcher ----------------
extern "C" void kernel_launch(void *const *d_in, const int *in_sizes, int n_in,
                              void *d_out, int out_size, void *d_ws, size_t ws_size,
                              hipStream_t stream) {
  const int *tokens = (const int *)d_in[0];
  const float *embed = (const float *)d_in[1];
  const float *Wx0 = (const float *)d_in[2];
  const float *Wh0 = (const float *)d_in[3];
  const float *b0 = (const float *)d_in[4];
  const float *Wfc0 = (const float *)d_in[5];
  const float *bfc0 = (const float *)d_in[6];
  const float *Wx1 = (const float *)d_in[7];
  const float *Wh1 = (const float *)d_in[8];
  const float *b1 = (const float *)d_in[9];
  const float *Wfc1 = (const float *)d_in[10];
  const float *bfc1 = (const float *)d_in[11];

  constexpr size_t NEED = 255856640;  // ~244 MiB (unchanged from validated R1)
  if (ws_size < NEED) {
    fprintf(stderr, "RNNLM kernel: ws too small (%zu < %zu)\n", ws_size, NEED);
    return;
  }
  char *ws = (char *)d_ws;
  u16 *xz = (u16 *)(ws + 0);               // [16384][4096] bf16 (reused L0/L1)
  u16 *hhi = (u16 *)(ws + 134217728);      // history [T][32][1024] (h0 then h1)
  u16 *hlo = (u16 *)(ws + 167772160);
  u16 *x1hi = (u16 *)(ws + 201326592);     // also x0hi (disjoint lifetimes)
  u16 *x1lo = (u16 *)(ws + 218103808);     // also x0lo
  u16 *WxT0hi = (u16 *)(ws + 234881024);
  u16 *WxT0lo = (u16 *)(ws + 239075328);
  u16 *WfcT0hi = (u16 *)(ws + 243269632);
  u16 *WfcT0lo = (u16 *)(ws + 244318208);
  u16 *WxT1hi = (u16 *)(ws + 245366784);
  u16 *WxT1lo = (u16 *)(ws + 249561088);
  u16 *WfcT1hi = (u16 *)(ws + 253755392);
  u16 *WfcT1lo = (u16 *)(ws + 254803968);
  // flags: carved from WxT regions (dead after their xz-GEMM). 1 KB each.
  int *flags0 = (int *)(ws + 234881024);
  int *flags1 = (int *)(ws + 245366784);

  // weight prepack (transpose + hi/lo split)
  k_packT<<<dim3(G4H / 32, DEMB / 32), dim3(32, 8), 0, stream>>>(Wx0, WxT0hi, WxT0lo, DEMB, G4H);
  k_packT<<<dim3(PDIM / 32, HDIM / 32), dim3(32, 8), 0, stream>>>(Wfc0, WfcT0hi, WfcT0lo, HDIM, PDIM);
  k_packT<<<dim3(G4H / 32, DEMB / 32), dim3(32, 8), 0, stream>>>(Wx1, WxT1hi, WxT1lo, DEMB, G4H);
  k_packT<<<dim3(PDIM / 32, HDIM / 32), dim3(32, 8), 0, stream>>>(Wfc1, WfcT1hi, WfcT1lo, HDIM, PDIM);
  // x0 = embed[tokens], hi/lo split  (rows m = b*T + t)
  k_gather_pack<<<4096, 256, 0, stream>>>(tokens, embed, x1hi, x1lo);

  // xz0 = x0 @ Wx0 + b0  -> bf16
  k_gemm<0><<<dim3(128 * 32), 256, 0, stream>>>(x1hi, x1lo, WxT0hi, WxT0lo, b0, xz, nullptr,
                                                16384, G4H, DEMB);
  // WxT0 now dead -> zero flags0 (1 KB; re-zeroed every graph replay)
  (void)hipMemsetAsync(flags0, 0, NWGR * sizeof(int), stream);
  // layer-0 recurrence (xz rows m = b*T + t)
  {
    const u16 *a0 = xz; const float *a1 = Wh0; u16 *a2 = hhi; u16 *a3 = hlo;
    int *a4 = flags0; int a5 = 0;
    void *args[] = {&a0, &a1, &a2, &a3, &a4, &a5};
    hipError_t e = hipLaunchCooperativeKernel((void *)k_recur, dim3(NWGR), dim3(256), args, 0, stream);
    if (e != hipSuccess) fprintf(stderr, "coop launch L0 failed: %d\n", (int)e);
  }
  // x1 = h0 @ Wfc0 + bfc0 -> hi/lo planes (rows m = t*32 + b)
  k_gemm<1><<<dim3(128 * 4), 256, 0, stream>>>(hhi, hlo, WfcT0hi, WfcT0lo, bfc0, x1hi, x1lo,
                                               16384, PDIM, HDIM);
  // xz1 = x1 @ Wx1 + b1 -> bf16
  k_gemm<0><<<dim3(128 * 32), 256, 0, stream>>>(x1hi, x1lo, WxT1hi, WxT1lo, b1, xz, nullptr,
                                                16384, G4H, DEMB);
  // WxT1 now dead -> zero flags1
  (void)hipMemsetAsync(flags1, 0, NWGR * sizeof(int), stream);
  // layer-1 recurrence (xz rows m = t*32 + b)
  {
    const u16 *a0 = xz; const float *a1 = Wh1; u16 *a2 = hhi; u16 *a3 = hlo;
    int *a4 = flags1; int a5 = 1;
    void *args[] = {&a0, &a1, &a2, &a3, &a4, &a5};
    hipError_t e = hipLaunchCooperativeKernel((void *)k_recur, dim3(NWGR), dim3(256), args, 0, stream);
    if (e != hipSuccess) fprintf(stderr, "coop launch L1 failed: %d\n", (int)e);
  }
  // out = h1 @ Wfc1 + bfc1 -> f32, scattered to (B,T,P)
  k_gemm<2><<<dim3(128 * 4), 256, 0, stream>>>(hhi, hlo, WfcT1hi, WfcT1lo, bfc1, d_out, nullptr,
                                               16384, PDIM, HDIM);
}

// Round 7
// 5651.962 us; speedup vs baseline: 1.1579x; 1.1579x over previous
//
#include <hip/hip_runtime.h>
#include <cstdio>
#include <cstdint>

typedef unsigned short u16;
typedef unsigned int u32;
typedef float f32x4 __attribute__((ext_vector_type(4)));
typedef short s16x8 __attribute__((ext_vector_type(8)));

#define DI __device__ __forceinline__

// problem sizes
#define BATCH 32
#define SEQT 512
#define HDIM 1024
#define PDIM 512
#define DEMB 512
#define G4H 4096

// ---------------- bf16 helpers (RNE + hi/lo split) ----------------
DI u16 f2bf(float f) {
  u32 u = __float_as_uint(f);
  return (u16)((u + 0x7fffu + ((u >> 16) & 1u)) >> 16);
}
DI float bf2f(u16 h) { return __uint_as_float(((u32)h) << 16); }
DI void split2(float f, u16 &hi, u16 &lo) {
  hi = f2bf(f);
  lo = f2bf(f - bf2f(hi));  // exact residual capture to ~2^-17 rel
}
DI f32x4 mfma16(s16x8 a, s16x8 b, f32x4 c) {
  return __builtin_amdgcn_mfma_f32_16x16x32_bf16(a, b, c, 0, 0, 0);
}
DI void dma16(const void *g, void *l) {
  __builtin_amdgcn_global_load_lds((const __attribute__((address_space(1))) void *)g,
                                   (__attribute__((address_space(3))) void *)l, 16, 0, 0);
}
// device-scope (sc1) ops: bypass L1/L2, talk straight to the coherence point.
// Zero cache-maintenance instructions anywhere in the recurrence handshake.
DI s16x8 ld128_dev(const u16 *p) {
  s16x8 r;
  asm volatile("global_load_dwordx4 %0, %1, off sc1" : "=v"(r) : "v"(p));
  return r;
}
DI void st16_dev(u16 *p, u16 v) {
  asm volatile("global_store_short %0, %1, off sc1" ::"v"(p), "v"((u32)v) : "memory");
}
DI void st32_dev(int *p, int v) {
  asm volatile("global_store_dword %0, %1, off sc1" ::"v"(p), "v"(v) : "memory");
}

// fast gate math: hardware exp2 + rcp (~1e-7 abs err on sigmoid/tanh outputs)
#if __has_builtin(__builtin_amdgcn_exp2f) && __has_builtin(__builtin_amdgcn_rcpf)
DI float fsig(float x) {
  return __builtin_amdgcn_rcpf(1.f + __builtin_amdgcn_exp2f(-1.4426950408889634f * x));
}
DI float ftanh(float x) {
  return 2.f * __builtin_amdgcn_rcpf(1.f + __builtin_amdgcn_exp2f(-2.8853900817779268f * x)) - 1.f;
}
#else
DI float fsig(float x) { return 1.f / (1.f + expf(-x)); }
DI float ftanh(float x) { return tanhf(x); }
#endif

// ---------------- embed gather -> x0 hi/lo planes ----------------
__global__ void k_gather_pack(const int *__restrict__ tokens, const float *__restrict__ embed,
                              u16 *__restrict__ xhi, u16 *__restrict__ xlo) {
  int idx = blockIdx.x * 256 + threadIdx.x;  // one thread per 8 elements
  int m = idx >> 6;                          // row 0..16383 (m = b*T + t)
  int k8 = (idx & 63) << 3;
  int tok = tokens[m];
  const float *src = embed + (size_t)tok * DEMB + k8;
  float4 a = *(const float4 *)src;
  float4 b = *(const float4 *)(src + 4);
  float v[8] = {a.x, a.y, a.z, a.w, b.x, b.y, b.z, b.w};
  union UV { u16 h[8]; int4 v; };
  UV uh, ul;
#pragma unroll
  for (int j = 0; j < 8; ++j) split2(v[j], uh.h[j], ul.h[j]);
  size_t o = (size_t)m * DEMB + k8;
  *(int4 *)(xhi + o) = uh.v;
  *(int4 *)(xlo + o) = ul.v;
}

// ------- transpose+split weights: W[K][N] f32 -> T[N][K] bf16 hi/lo -------
__global__ void k_packT(const float *__restrict__ W, u16 *__restrict__ Thi, u16 *__restrict__ Tlo,
                        int K, int N) {
  __shared__ float tile[32][33];
  int n0 = blockIdx.x * 32, k0 = blockIdx.y * 32;
  int tx = threadIdx.x, ty = threadIdx.y;  // (32,8)
#pragma unroll
  for (int i = 0; i < 4; ++i) tile[ty + 8 * i][tx] = W[(size_t)(k0 + ty + 8 * i) * N + n0 + tx];
  __syncthreads();
#pragma unroll
  for (int i = 0; i < 4; ++i) {
    int n = ty + 8 * i;
    u16 hi, lo;
    split2(tile[tx][n], hi, lo);
    size_t o = (size_t)(n0 + n) * K + k0 + tx;
    Thi[o] = hi;
    Tlo[o] = lo;
  }
}

// ------- elementwise hi/lo split (row-major, no transpose) -------
__global__ void k_split(const float *__restrict__ W, u16 *__restrict__ hi, u16 *__restrict__ lo,
                        int n) {
  int i = blockIdx.x * 256 + threadIdx.x;
  if (i < n) split2(W[i], hi[i], lo[i]);
}

// ------- beff = bfc0 @ Wx1 + b1  (f32 [4096]) -------
__global__ void k_beff(const float *__restrict__ bfc0, const float *__restrict__ Wx1,
                       const float *__restrict__ b1, float *__restrict__ beff) {
  int n = blockIdx.x * 256 + threadIdx.x;  // 4096
  float acc = b1[n];
  for (int j = 0; j < PDIM; ++j) acc += bfc0[j] * Wx1[(size_t)j * G4H + n];
  beff[n] = acc;
}

// ---------------- generic bf16x3 GEMM ----------------
// C[M][N] = A[M][K] * B^T-source[N][K] + bias, A/B given as bf16 hi/lo planes.
// 128x128 tile, BK=64, 4 waves. Both tiles DMA-staged via global_load_lds(16)
// into XOR-swizzled LDS (swizzle folded into per-lane SOURCE address).
// OM: 0 = bf16 out, 2 = f32 out scattered to (B,T,P).
// SA: 1 = A is single bf16 (Alo ignored; plane 1 zero-filled once).
template <int OM, int SA>
__global__ __launch_bounds__(256, 2) void k_gemm(const u16 *__restrict__ Ahi, const u16 *__restrict__ Alo,
                                                 const u16 *__restrict__ Bhi, const u16 *__restrict__ Blo,
                                                 const float *__restrict__ bias, void *__restrict__ out0,
                                                 int M, int N, int K) {
  __shared__ u16 sP[4][128 * 64];  // planes: Ahi, Alo, Bhi, Blo (16KB each)
  const int tid = threadIdx.x;
  const int w = tid >> 6, lane = tid & 63;
  const int la15 = lane & 15, la4 = lane >> 4;
  const int nbn = N >> 7;
  const int bm = blockIdx.x / nbn, bn = blockIdx.x % nbn;
  const u16 *src = (w == 0) ? Ahi : (w == 1) ? Alo : (w == 2) ? Bhi : Blo;
  const int rowbase = (w < 2) ? bm * 128 : bn * 128;
  char *lds = (char *)&sP[w][0];

  if (SA) {  // zero the Alo plane once; its MFMAs then contribute +0
    for (int i = tid; i < 2048; i += 256) ((unsigned long long *)&sP[1][0])[i] = 0ULL;
  }

  f32x4 acc[2][8] = {};
  for (int kb = 0; kb < K; kb += 64) {
    if (!(SA && w == 1)) {
#pragma unroll
      for (int i = 0; i < 16; ++i) {
        int s = i * 64 + lane;            // 16B slot id
        int row = s >> 3;                 // 8 slots per 128B row
        int k16 = (s & 7) ^ (row & 7);    // inverse of read swizzle
        dma16(src + (size_t)(rowbase + row) * K + kb + k16 * 8, lds + i * 1024);
      }
    }
    asm volatile("s_waitcnt vmcnt(0)" ::: "memory");
    __syncthreads();
#pragma unroll
    for (int ksl = 0; ksl < 2; ++ksl) {
      s16x8 ah[2], al[2];
#pragma unroll
      for (int rf = 0; rf < 2; ++rf) {
        int row = 32 * w + 16 * rf + la15;
        int slot = row * 8 + ((4 * ksl + la4) ^ (row & 7));
        ah[rf] = *(const s16x8 *)((const char *)&sP[0][0] + slot * 16);
        al[rf] = *(const s16x8 *)((const char *)&sP[1][0] + slot * 16);
      }
#pragma unroll
      for (int cf = 0; cf < 8; ++cf) {
        int col = 16 * cf + la15;
        int slot = col * 8 + ((4 * ksl + la4) ^ (col & 7));
        s16x8 bh = *(const s16x8 *)((const char *)&sP[2][0] + slot * 16);
        s16x8 bl = *(const s16x8 *)((const char *)&sP[3][0] + slot * 16);
#pragma unroll
        for (int rf = 0; rf < 2; ++rf) {
          acc[rf][cf] = mfma16(ah[rf], bh, acc[rf][cf]);
          acc[rf][cf] = mfma16(ah[rf], bl, acc[rf][cf]);
          acc[rf][cf] = mfma16(al[rf], bh, acc[rf][cf]);
        }
      }
    }
    __syncthreads();
  }
  // epilogue: D[r][c], r = 4*(lane>>4)+q (M), c = lane&15 (N)  [m89-verified]
#pragma unroll
  for (int rf = 0; rf < 2; ++rf) {
#pragma unroll
    for (int cf = 0; cf < 8; ++cf) {
      int c = bn * 128 + 16 * cf + la15;
      float bv = bias ? bias[c] : 0.f;
#pragma unroll
      for (int q = 0; q < 4; ++q) {
        int r = bm * 128 + 32 * w + 16 * rf + 4 * la4 + q;
        float v = acc[rf][cf][q] + bv;
        if (OM == 0) {
          ((u16 *)out0)[(size_t)r * N + c] = f2bf(v);
        } else {
          int b2 = r & 31, tt = r >> 5;  // A rows are m = t*32 + b
          ((float *)out0)[((size_t)b2 * SEQT + tt) * PDIM + c] = v;
        }
      }
    }
  }
}

// ---------------- pipelined 2-layer persistent LSTM recurrence ----------------
// 256 WGs x 256 threads, 1 WG/CU. wg<128: layer 0 (g=wg); wg>=128: layer 1.
// Each WG: ALL 32 batch rows x 8 h-cols (32 z-cols). Weights SINGLE bf16 in
// LDS, XOR-swizzled: sW = Wh slice (64 KB); L1 also sE = Weff slice (64 KB),
// where Weff = Wfc0 @ Wx1 folds layer-1's input path into one GEMM:
//   z1[t] = h0[t] @ Weff + h1[t-1] @ Wh1 + beff.
// L1 lags L0 by one step -> both layers finish in ~513 step-slots (vs 1024).
// Handshake = proven R3 protocol: write-once per-step hist buffers, parallel
// per-thread 2B sc1 stores, per-wave vmcnt(0), barrier, one monotonic sc1
// flag store per WG; consumers: wave0 polls flags, sc1 dwordx4 h loads.
// L0 polls flags0>=t; L1 polls flags0>=t+1 (h0[t]) and flags1>=t (h1[t-1]).
// L0 never waits on L1 -> guaranteed progress; hist write-once => no reuse races.
__global__ __launch_bounds__(256, 1) void k_recur_pipe(
    const u16 *__restrict__ xz0, const float *__restrict__ Wh0, const float *__restrict__ Wh1,
    const u16 *__restrict__ Weff, const float *__restrict__ beff,
    u16 *h0h, u16 *h1h, int *flags) {
  __shared__ u16 sW[32 * 1024];      // 64 KB: layer's Wh slice [zc][k] swizzled
  __shared__ u16 sE[32 * 1024];      // 64 KB: L1 Weff slice (unused by L0)
  __shared__ float zacc[4][32][33];  // per-wave K-partials (+1 col pad)
  __shared__ float sC[256];          // cell state c[32 rows][8 cols]
  const int tid = threadIdx.x;
  const int w = tid >> 6, lane = tid & 63;
  const int la15 = lane & 15, la4 = lane >> 4;
  const int wg = blockIdx.x;
  const int layer = wg >> 7;
  const int g = wg & 127;  // 8 h-cols: [8g, 8g+8)

  // stage weights (single bf16, swizzled), once per launch
  const float *Wh = layer ? Wh1 : Wh0;
  for (int i2 = tid; i2 < 32 * 1024; i2 += 256) {
    int zc = i2 & 31;
    int k = i2 >> 5;
    int gcol = (zc >> 3) * HDIM + 8 * g + (zc & 7);
    int boff = zc * 2048 + ((((k >> 3) ^ (zc & 7))) << 4) + (k & 7) * 2;
    *(u16 *)((char *)sW + boff) = f2bf(Wh[(size_t)k * G4H + gcol]);
    if (layer) *(u16 *)((char *)sE + boff) = Weff[(size_t)k * G4H + gcol];
  }
  sC[tid] = 0.f;
  __syncthreads();

  const int r_g = tid >> 3, hc = tid & 7;  // gate coords: 32 rows x 8 cols
  const int ks0 = 8 * w;                   // wave's k-slice (256 k)
  u16 *histW = layer ? h1h : h0h;

  float bef[4] = {0.f, 0.f, 0.f, 0.f};
  if (layer) {
#pragma unroll
    for (int gi = 0; gi < 4; ++gi) bef[gi] = beff[gi * HDIM + 8 * g + hc];
  }

  for (int t = 0; t < SEQT; ++t) {
    // L0: prefetch xz0[t] (normal loads, hidden under poll)
    float xzv[4] = {0.f, 0.f, 0.f, 0.f};
    if (!layer) {
      const u16 *px = xz0 + ((size_t)r_g * SEQT + t) * G4H + 8 * g + hc;
#pragma unroll
      for (int gi = 0; gi < 4; ++gi) xzv[gi] = bf2f(px[(size_t)gi * HDIM]);
    }
    // wave0 polls producer flags
    if (w == 0) {
      if (!layer) {
        if (t > 0) {
          const int *dp = flags + lane;
          for (long tries = 0;; ++tries) {
            int a = __hip_atomic_load(dp, __ATOMIC_RELAXED, __HIP_MEMORY_SCOPE_AGENT);
            int b = __hip_atomic_load(dp + 64, __ATOMIC_RELAXED, __HIP_MEMORY_SCOPE_AGENT);
            if (__all(a >= t && b >= t)) break;
            if (tries > (1L << 22)) break;
            __builtin_amdgcn_s_sleep(1);
          }
        }
      } else {
        const int *d0 = flags + lane;
        const int *d1 = flags + 128 + lane;
        for (long tries = 0;; ++tries) {
          int a = __hip_atomic_load(d0, __ATOMIC_RELAXED, __HIP_MEMORY_SCOPE_AGENT);
          int b = __hip_atomic_load(d0 + 64, __ATOMIC_RELAXED, __HIP_MEMORY_SCOPE_AGENT);
          bool ok = (a >= t + 1 && b >= t + 1);
          if (t > 0) {
            int c = __hip_atomic_load(d1, __ATOMIC_RELAXED, __HIP_MEMORY_SCOPE_AGENT);
            int d = __hip_atomic_load(d1 + 64, __ATOMIC_RELAXED, __HIP_MEMORY_SCOPE_AGENT);
            ok = ok && (c >= t && d >= t);
          }
          if (__all(ok)) break;
          if (tries > (1L << 22)) break;
          __builtin_amdgcn_s_sleep(1);
        }
      }
    }
    __syncthreads();  // required hist regions globally visible

    const bool doWh = (t > 0);
    const size_t tm1 = doWh ? (size_t)(t - 1) : 0;
    const u16 *pAwh = (layer ? h1h : h0h) + tm1 * 32 * HDIM;  // h[t-1]
    const u16 *pAwe = h0h + (size_t)t * 32 * HDIM;            // h0[t] (L1)

#pragma unroll
    for (int rt = 0; rt < 2; ++rt) {
      const int row = 16 * rt + la15;
      s16x8 aw[8], ae[8];
      if (doWh) {
#pragma unroll
        for (int j8 = 0; j8 < 8; ++j8)
          aw[j8] = ld128_dev(pAwh + (size_t)row * HDIM + 32 * (ks0 + j8) + 8 * la4);
      }
      if (layer) {
#pragma unroll
        for (int j8 = 0; j8 < 8; ++j8)
          ae[j8] = ld128_dev(pAwe + (size_t)row * HDIM + 32 * (ks0 + j8) + 8 * la4);
      }
      if (doWh || layer) {
        asm volatile("s_waitcnt vmcnt(0)" ::: "memory");
        __builtin_amdgcn_sched_barrier(0);  // rule 18
        f32x4 acc[2] = {};
#pragma unroll
        for (int j8 = 0; j8 < 8; ++j8) {
#pragma unroll
          for (int cf = 0; cf < 2; ++cf) {
            int zc = 16 * cf + la15;
            int slot = (4 * (ks0 + j8) + la4) ^ (zc & 7);
            int boff = zc * 2048 + (slot << 4);
            if (doWh) acc[cf] = mfma16(aw[j8], *(const s16x8 *)((const char *)sW + boff), acc[cf]);
            if (layer) acc[cf] = mfma16(ae[j8], *(const s16x8 *)((const char *)sE + boff), acc[cf]);
          }
        }
#pragma unroll
        for (int cf = 0; cf < 2; ++cf)
#pragma unroll
          for (int q = 0; q < 4; ++q)
            zacc[w][16 * rt + 4 * la4 + q][16 * cf + la15] = acc[cf][q];
      }
    }
    __syncthreads();
    // gates: all 256 threads (32 rows x 8 cols)
    {
      float z4[4];
#pragma unroll
      for (int gi = 0; gi < 4; ++gi) {
        float s = layer ? bef[gi] : xzv[gi];
        if (t > 0 || layer) {
          int zc = gi * 8 + hc;
          s += zacc[0][r_g][zc] + zacc[1][r_g][zc] + zacc[2][r_g][zc] + zacc[3][r_g][zc];
        }
        z4[gi] = s;
      }
      float ig = fsig(z4[0]);
      float fg = fsig(z4[1]);
      float gg = ftanh(z4[2]);
      float og = fsig(z4[3]);
      float c = fg * sC[tid] + ig * gg;
      sC[tid] = c;
      float h = og * ftanh(c);
      st16_dev(histW + ((size_t)t * 32 + r_g) * HDIM + 8 * g + hc, f2bf(h));
    }
    asm volatile("s_waitcnt vmcnt(0)" ::: "memory");  // own h-stores at L3
    __syncthreads();                                  // whole WG's stores done
    if (tid == 0) st32_dev(flags + 128 * layer + g, t + 1);
  }
}

// ---------------- host launcher ----------------
extern "C" void kernel_launch(void *const *d_in, const int *in_sizes, int n_in,
                              void *d_out, int out_size, void *d_ws, size_t ws_size,
                              hipStream_t stream) {
  const int *tokens = (const int *)d_in[0];
  const float *embed = (const float *)d_in[1];
  const float *Wx0 = (const float *)d_in[2];
  const float *Wh0 = (const float *)d_in[3];
  const float *b0 = (const float *)d_in[4];
  const float *Wfc0 = (const float *)d_in[5];
  const float *bfc0 = (const float *)d_in[6];
  const float *Wx1 = (const float *)d_in[7];
  const float *Wh1 = (const float *)d_in[8];
  const float *b1 = (const float *)d_in[9];
  const float *Wfc1 = (const float *)d_in[10];
  const float *bfc1 = (const float *)d_in[11];

  constexpr size_t NEED = 255856640;  // ~244 MiB (unchanged from validated R1)
  if (ws_size < NEED) {
    fprintf(stderr, "RNNLM kernel: ws too small (%zu < %zu)\n", ws_size, NEED);
    return;
  }
  char *ws = (char *)d_ws;
  u16 *xz0 = (u16 *)(ws + 0);           // [16384][4096] bf16, rows m=b*T+t
  u16 *h0h = (u16 *)(ws + 134217728);   // h0 hist [512][32][1024] bf16 (32 MB)
  u16 *h1h = (u16 *)(ws + 167772160);   // h1 hist (32 MB)
  u16 *x0hi = (u16 *)(ws + 201326592);  // 16 MB, dead after xz0 GEMM
  u16 *x0lo = (u16 *)(ws + 218103808);  // 16 MB, dead after xz0 GEMM
  // carved into the x0 region AFTER the xz0 GEMM (stream-ordered):
  u16 *Weff = (u16 *)(ws + 201326592);      // [1024][4096] bf16 (8 MB)
  u16 *Wfc0hi = (u16 *)(ws + 209715200);    // [1024][512] (1 MB)
  u16 *Wfc0lo = (u16 *)(ws + 210763776);    // 1 MB
  u16 *WfcT1hi = (u16 *)(ws + 211812352);   // [512][1024] (1 MB)
  u16 *WfcT1lo = (u16 *)(ws + 212860928);   // 1 MB
  float *beff = (float *)(ws + 213909504);  // [4096] f32 (16 KB)
  int *flags = (int *)(ws + 213925888);     // [256] (1 KB)
  // own regions:
  u16 *WxT0hi = (u16 *)(ws + 234881024);  // [4096][512] (4 MB)
  u16 *WxT0lo = (u16 *)(ws + 239075328);
  u16 *WxT1hi = (u16 *)(ws + 243269632);  // [4096][512] (4 MB)
  u16 *WxT1lo = (u16 *)(ws + 247463936);  // ends 251658240 < NEED

  // prepack (regions disjoint from x0)
  k_packT<<<dim3(G4H / 32, DEMB / 32), dim3(32, 8), 0, stream>>>(Wx0, WxT0hi, WxT0lo, DEMB, G4H);
  k_packT<<<dim3(G4H / 32, DEMB / 32), dim3(32, 8), 0, stream>>>(Wx1, WxT1hi, WxT1lo, DEMB, G4H);
  // x0 = embed[tokens] hi/lo
  k_gather_pack<<<4096, 256, 0, stream>>>(tokens, embed, x0hi, x0lo);
  // xz0 = x0 @ Wx0 + b0 -> bf16 (rows m = b*T + t)
  k_gemm<0, 0><<<dim3(128 * 32), 256, 0, stream>>>(x0hi, x0lo, WxT0hi, WxT0lo, b0, xz0,
                                                   16384, G4H, DEMB);
  // x0 now dead: build fused layer-1 input path in its place
  k_split<<<2048, 256, 0, stream>>>(Wfc0, Wfc0hi, Wfc0lo, HDIM * PDIM);
  k_packT<<<dim3(PDIM / 32, HDIM / 32), dim3(32, 8), 0, stream>>>(Wfc1, WfcT1hi, WfcT1lo, HDIM, PDIM);
  k_beff<<<16, 256, 0, stream>>>(bfc0, Wx1, b1, beff);
  (void)hipMemsetAsync(flags, 0, 256 * sizeof(int), stream);
  // Weff = Wfc0 @ Wx1 -> bf16 [1024][4096]  (A=Wfc0 hi/lo, B=WxT1 hi/lo)
  k_gemm<0, 0><<<dim3(8 * 32), 256, 0, stream>>>(Wfc0hi, Wfc0lo, WxT1hi, WxT1lo, nullptr, Weff,
                                                 1024, G4H, PDIM);
  // pipelined both-layer recurrence (one cooperative dispatch)
  {
    const u16 *a0 = xz0; const float *a1 = Wh0; const float *a2 = Wh1;
    const u16 *a3 = Weff; const float *a4 = beff;
    u16 *a5 = h0h; u16 *a6 = h1h; int *a7 = flags;
    void *args[] = {&a0, &a1, &a2, &a3, &a4, &a5, &a6, &a7};
    hipError_t e = hipLaunchCooperativeKernel((void *)k_recur_pipe, dim3(256), dim3(256), args, 0, stream);
    if (e != hipSuccess) fprintf(stderr, "coop launch failed: %d\n", (int)e);
  }
  // out = h1 @ Wfc1 + bfc1 -> f32 scattered to (B,T,P)  (A single bf16)
  k_gemm<2, 1><<<dim3(128 * 4), 256, 0, stream>>>(h1h, h1h, WfcT1hi, WfcT1lo, bfc1, d_out,
                                                  16384, PDIM, HDIM);
}

// Round 9
// 5199.445 us; speedup vs baseline: 1.2587x; 1.0870x over previous
//
#include <hip/hip_runtime.h>
#include <cstdio>
#include <cstdint>

typedef unsigned short u16;
typedef unsigned int u32;
typedef float f32x4 __attribute__((ext_vector_type(4)));
typedef short s16x8 __attribute__((ext_vector_type(8)));

#define DI __device__ __forceinline__

// problem sizes
#define BATCH 32
#define SEQT 512
#define HDIM 1024
#define PDIM 512
#define DEMB 512
#define G4H 4096

// ---------------- bf16 helpers (RNE + hi/lo split) ----------------
DI u16 f2bf(float f) {
  u32 u = __float_as_uint(f);
  return (u16)((u + 0x7fffu + ((u >> 16) & 1u)) >> 16);
}
DI float bf2f(u16 h) { return __uint_as_float(((u32)h) << 16); }
DI void split2(float f, u16 &hi, u16 &lo) {
  hi = f2bf(f);
  lo = f2bf(f - bf2f(hi));  // exact residual capture to ~2^-17 rel
}
DI f32x4 mfma16(s16x8 a, s16x8 b, f32x4 c) {
  return __builtin_amdgcn_mfma_f32_16x16x32_bf16(a, b, c, 0, 0, 0);
}
DI void dma16(const void *g, void *l) {
  __builtin_amdgcn_global_load_lds((const __attribute__((address_space(1))) void *)g,
                                   (__attribute__((address_space(3))) void *)l, 16, 0, 0);
}
// device-scope (sc1) ops: bypass L1/L2, talk straight to the coherence point.
// Zero cache-maintenance instructions anywhere in the recurrence handshake.
// RULE-18/20 DISCIPLINE (R8 lesson): every asm-load's output must be consumed
// (or parked in LDS) IMMEDIATELY after a vmcnt(0)+sched_barrier(0) — never
// held live across a register-pressure-heavy region (spill saves pre-retire
// garbage).
DI s16x8 ld128_dev(const u16 *p) {
  s16x8 r;
  asm volatile("global_load_dwordx4 %0, %1, off sc1" : "=v"(r) : "v"(p));
  return r;
}
DI f32x4 ldf4_dev(const float *p) {
  f32x4 r;
  asm volatile("global_load_dwordx4 %0, %1, off sc1" : "=v"(r) : "v"(p));
  return r;
}
DI void st16_dev(u16 *p, u16 v) {
  asm volatile("global_store_short %0, %1, off sc1" ::"v"(p), "v"((u32)v) : "memory");
}
DI void st32_dev(int *p, int v) {
  asm volatile("global_store_dword %0, %1, off sc1" ::"v"(p), "v"(v) : "memory");
}
DI void st128f_dev(float *p, f32x4 v) {
  asm volatile("global_store_dwordx4 %0, %1, off sc1" ::"v"(p), "v"(v) : "memory");
}

// fast gate math: hardware exp2 + rcp (~1e-7 abs err on sigmoid/tanh outputs)
#if __has_builtin(__builtin_amdgcn_exp2f) && __has_builtin(__builtin_amdgcn_rcpf)
DI float fsig(float x) {
  return __builtin_amdgcn_rcpf(1.f + __builtin_amdgcn_exp2f(-1.4426950408889634f * x));
}
DI float ftanh(float x) {
  return 2.f * __builtin_amdgcn_rcpf(1.f + __builtin_amdgcn_exp2f(-2.8853900817779268f * x)) - 1.f;
}
#else
DI float fsig(float x) { return 1.f / (1.f + expf(-x)); }
DI float ftanh(float x) { return tanhf(x); }
#endif

// ---------------- embed gather -> x0 hi/lo planes ----------------
__global__ void k_gather_pack(const int *__restrict__ tokens, const float *__restrict__ embed,
                              u16 *__restrict__ xhi, u16 *__restrict__ xlo) {
  int idx = blockIdx.x * 256 + threadIdx.x;  // one thread per 8 elements
  int m = idx >> 6;                          // row 0..16383 (m = b*T + t)
  int k8 = (idx & 63) << 3;
  int tok = tokens[m];
  const float *src = embed + (size_t)tok * DEMB + k8;
  float4 a = *(const float4 *)src;
  float4 b = *(const float4 *)(src + 4);
  float v[8] = {a.x, a.y, a.z, a.w, b.x, b.y, b.z, b.w};
  union UV { u16 h[8]; int4 v; };
  UV uh, ul;
#pragma unroll
  for (int j = 0; j < 8; ++j) split2(v[j], uh.h[j], ul.h[j]);
  size_t o = (size_t)m * DEMB + k8;
  *(int4 *)(xhi + o) = uh.v;
  *(int4 *)(xlo + o) = ul.v;
}

// ------- transpose+split weights: W[K][N] f32 -> T[N][K] bf16 hi/lo -------
__global__ void k_packT(const float *__restrict__ W, u16 *__restrict__ Thi, u16 *__restrict__ Tlo,
                        int K, int N) {
  __shared__ float tile[32][33];
  int n0 = blockIdx.x * 32, k0 = blockIdx.y * 32;
  int tx = threadIdx.x, ty = threadIdx.y;  // (32,8)
#pragma unroll
  for (int i = 0; i < 4; ++i) tile[ty + 8 * i][tx] = W[(size_t)(k0 + ty + 8 * i) * N + n0 + tx];
  __syncthreads();
#pragma unroll
  for (int i = 0; i < 4; ++i) {
    int n = ty + 8 * i;
    u16 hi, lo;
    split2(tile[tx][n], hi, lo);
    size_t o = (size_t)(n0 + n) * K + k0 + tx;
    Thi[o] = hi;
    Tlo[o] = lo;
  }
}

// ------- elementwise hi/lo split (row-major, no transpose) -------
__global__ void k_split(const float *__restrict__ W, u16 *__restrict__ hi, u16 *__restrict__ lo,
                        int n) {
  int i = blockIdx.x * 256 + threadIdx.x;
  if (i < n) split2(W[i], hi[i], lo[i]);
}

// ------- beff = bfc0 @ Wx1 + b1  (f32 [4096]) -------
__global__ void k_beff(const float *__restrict__ bfc0, const float *__restrict__ Wx1,
                       const float *__restrict__ b1, float *__restrict__ beff) {
  int n = blockIdx.x * 256 + threadIdx.x;  // 4096
  float acc = b1[n];
  for (int j = 0; j < PDIM; ++j) acc += bfc0[j] * Wx1[(size_t)j * G4H + n];
  beff[n] = acc;
}

// ---------------- generic bf16x3 GEMM ----------------
// C[M][N] = A[M][K] * B^T-source[N][K] + bias, A/B given as bf16 hi/lo planes.
// 128x128 tile, BK=64, 4 waves. Both tiles DMA-staged via global_load_lds(16)
// into XOR-swizzled LDS (swizzle folded into per-lane SOURCE address).
// OM: 0 = bf16 out, 2 = f32 out scattered to (B,T,P).
// SA: 1 = A is single bf16 (Alo ignored; plane 1 zero-filled once).
template <int OM, int SA>
__global__ __launch_bounds__(256, 2) void k_gemm(const u16 *__restrict__ Ahi, const u16 *__restrict__ Alo,
                                                 const u16 *__restrict__ Bhi, const u16 *__restrict__ Blo,
                                                 const float *__restrict__ bias, void *__restrict__ out0,
                                                 int M, int N, int K) {
  __shared__ u16 sP[4][128 * 64];  // planes: Ahi, Alo, Bhi, Blo (16KB each)
  const int tid = threadIdx.x;
  const int w = tid >> 6, lane = tid & 63;
  const int la15 = lane & 15, la4 = lane >> 4;
  const int nbn = N >> 7;
  const int bm = blockIdx.x / nbn, bn = blockIdx.x % nbn;
  const u16 *src = (w == 0) ? Ahi : (w == 1) ? Alo : (w == 2) ? Bhi : Blo;
  const int rowbase = (w < 2) ? bm * 128 : bn * 128;
  char *lds = (char *)&sP[w][0];

  if (SA) {  // zero the Alo plane once; its MFMAs then contribute +0
    for (int i = tid; i < 2048; i += 256) ((unsigned long long *)&sP[1][0])[i] = 0ULL;
  }

  f32x4 acc[2][8] = {};
  for (int kb = 0; kb < K; kb += 64) {
    if (!(SA && w == 1)) {
#pragma unroll
      for (int i = 0; i < 16; ++i) {
        int s = i * 64 + lane;            // 16B slot id
        int row = s >> 3;                 // 8 slots per 128B row
        int k16 = (s & 7) ^ (row & 7);    // inverse of read swizzle
        dma16(src + (size_t)(rowbase + row) * K + kb + k16 * 8, lds + i * 1024);
      }
    }
    asm volatile("s_waitcnt vmcnt(0)" ::: "memory");
    __syncthreads();
#pragma unroll
    for (int ksl = 0; ksl < 2; ++ksl) {
      s16x8 ah[2], al[2];
#pragma unroll
      for (int rf = 0; rf < 2; ++rf) {
        int row = 32 * w + 16 * rf + la15;
        int slot = row * 8 + ((4 * ksl + la4) ^ (row & 7));
        ah[rf] = *(const s16x8 *)((const char *)&sP[0][0] + slot * 16);
        al[rf] = *(const s16x8 *)((const char *)&sP[1][0] + slot * 16);
      }
#pragma unroll
      for (int cf = 0; cf < 8; ++cf) {
        int col = 16 * cf + la15;
        int slot = col * 8 + ((4 * ksl + la4) ^ (col & 7));
        s16x8 bh = *(const s16x8 *)((const char *)&sP[2][0] + slot * 16);
        s16x8 bl = *(const s16x8 *)((const char *)&sP[3][0] + slot * 16);
#pragma unroll
        for (int rf = 0; rf < 2; ++rf) {
          acc[rf][cf] = mfma16(ah[rf], bh, acc[rf][cf]);
          acc[rf][cf] = mfma16(ah[rf], bl, acc[rf][cf]);
          acc[rf][cf] = mfma16(al[rf], bh, acc[rf][cf]);
        }
      }
    }
    __syncthreads();
  }
  // epilogue: D[r][c], r = 4*(lane>>4)+q (M), c = lane&15 (N)  [m89-verified]
#pragma unroll
  for (int rf = 0; rf < 2; ++rf) {
#pragma unroll
    for (int cf = 0; cf < 8; ++cf) {
      int c = bn * 128 + 16 * cf + la15;
      float bv = bias ? bias[c] : 0.f;
#pragma unroll
      for (int q = 0; q < 4; ++q) {
        int r = bm * 128 + 32 * w + 16 * rf + 4 * la4 + q;
        float v = acc[rf][cf][q] + bv;
        if (OM == 0) {
          ((u16 *)out0)[(size_t)r * N + c] = f2bf(v);
        } else {
          int b2 = r & 31, tt = r >> 5;  // A rows are m = t*32 + b
          ((float *)out0)[((size_t)b2 * SEQT + tt) * PDIM + c] = v;
        }
      }
    }
  }
}

// ---------------- pipelined 2-layer persistent LSTM recurrence (R9) ----------------
// Same design as R8 (balanced pipe, zeffP f32 partial ring, monotonic flags)
// with the two hazard-class fixes:
//  (1) no long-lived asm-load outputs: L1's zeff partials come in as 4 f32x4
//      vector loads -> vmcnt(0)+sched_barrier IMMEDIATELY -> summed -> parked
//      in LDS zE[32][33]; gates read LDS. (R8 kept 16 scalar asm outputs live
//      across the whole MFMA region -> spill saves pre-retire garbage.)
//  (2) one L3 round-trip per step: all 16 A-tile ld128 issued before a single
//      vmcnt, in both layers.
__global__ __launch_bounds__(256, 1) void k_recur_pipe(
    const u16 *__restrict__ xz0, const float *__restrict__ Wh0, const float *__restrict__ Wh1,
    const u16 *__restrict__ Weff, const float *__restrict__ beff,
    u16 *h0h, u16 *h1h, float *zeffP, int *flags) {
  __shared__ u16 sW[32 * 1024];      // 64 KB: layer's Wh slice [zc][k] swizzled
  __shared__ u16 sE[32 * 1024];      // 64 KB: L0's Weff slice (unused by L1)
  __shared__ float zacc[4][32][33];  // per-wave K-partials (+1 col pad)
  __shared__ float sC[256];          // cell state c[32 rows][8 cols]
  __shared__ float zE[32][33];       // L1: summed zeff partials [zc][row]
  const int tid = threadIdx.x;
  const int w = tid >> 6, lane = tid & 63;
  const int la15 = lane & 15, la4 = lane >> 4;
  const int wg = blockIdx.x;
  const int layer = wg >> 7;
  const int g = wg & 127;  // 8 h-cols: [8g, 8g+8)

  // stage weights (single bf16, swizzled), once per launch
  const float *Wh = layer ? Wh1 : Wh0;
  for (int i2 = tid; i2 < 32 * 1024; i2 += 256) {
    int zc = i2 & 31;
    int k = i2 >> 5;
    int gcol = (zc >> 3) * HDIM + 8 * g + (zc & 7);
    int boff = zc * 2048 + ((((k >> 3) ^ (zc & 7))) << 4) + (k & 7) * 2;
    *(u16 *)((char *)sW + boff) = f2bf(Wh[(size_t)k * G4H + gcol]);
    if (!layer) *(u16 *)((char *)sE + boff) = Weff[(size_t)k * G4H + gcol];
  }
  sC[tid] = 0.f;
  __syncthreads();

  const int r_g = tid >> 3, hc = tid & 7;  // gate coords: 32 rows x 8 cols
  const int ks0 = 8 * w;                   // wave's k-slice (256 k)

  if (!layer) {
    // ---------------- layer 0 (513 slots) ----------------
    for (int t = 0; t <= SEQT; ++t) {
      const bool last = (t == SEQT);
      float xzv[4] = {0.f, 0.f, 0.f, 0.f};
      if (!last) {
        const u16 *px = xz0 + ((size_t)r_g * SEQT + t) * G4H + 8 * g + hc;
#pragma unroll
        for (int gi = 0; gi < 4; ++gi) xzv[gi] = bf2f(px[(size_t)gi * HDIM]);
      }
      if (w == 0 && t > 0) {
        const int *f0 = flags + lane;
        const int *f1 = flags + 128 + lane;
        const int bp = t - 16;
        for (long tries = 0;; ++tries) {
          int a = __hip_atomic_load(f0, __ATOMIC_RELAXED, __HIP_MEMORY_SCOPE_AGENT);
          int b = __hip_atomic_load(f0 + 64, __ATOMIC_RELAXED, __HIP_MEMORY_SCOPE_AGENT);
          bool ok = (a >= t && b >= t);
          if (t > 16) {  // ring back-pressure (slot reuse after 16 steps)
            int c = __hip_atomic_load(f1, __ATOMIC_RELAXED, __HIP_MEMORY_SCOPE_AGENT);
            int d = __hip_atomic_load(f1 + 64, __ATOMIC_RELAXED, __HIP_MEMORY_SCOPE_AGENT);
            ok = ok && (c >= bp && d >= bp);
          }
          if (__all(ok)) break;
          if (tries > (1L << 22)) break;  // safety valve
          __builtin_amdgcn_s_sleep(1);
        }
      }
      __syncthreads();
      if (t > 0) {
        const u16 *pA = h0h + (size_t)(t - 1) * 32 * HDIM;
        float *zb = zeffP + ((((size_t)((t - 1) & 15) * 128 + g) * 4 + w) << 10);
        // issue ALL 16 A-loads (both row halves), then one vmcnt
        s16x8 aw0[8], aw1[8];
#pragma unroll
        for (int j8 = 0; j8 < 8; ++j8)
          aw0[j8] = ld128_dev(pA + (size_t)la15 * HDIM + 32 * (ks0 + j8) + 8 * la4);
#pragma unroll
        for (int j8 = 0; j8 < 8; ++j8)
          aw1[j8] = ld128_dev(pA + (size_t)(16 + la15) * HDIM + 32 * (ks0 + j8) + 8 * la4);
        asm volatile("s_waitcnt vmcnt(0)" ::: "memory");
        __builtin_amdgcn_sched_barrier(0);  // rule 18
        // rows 0..15
        {
          f32x4 acc0[2] = {}, accE[2] = {};
#pragma unroll
          for (int j8 = 0; j8 < 8; ++j8) {
#pragma unroll
            for (int cf = 0; cf < 2; ++cf) {
              int zc = 16 * cf + la15;
              int sl = (4 * (ks0 + j8) + la4) ^ (zc & 7);
              int boff = zc * 2048 + (sl << 4);
              if (!last) acc0[cf] = mfma16(aw0[j8], *(const s16x8 *)((const char *)sW + boff), acc0[cf]);
              accE[cf] = mfma16(aw0[j8], *(const s16x8 *)((const char *)sE + boff), accE[cf]);
            }
          }
#pragma unroll
          for (int cf = 0; cf < 2; ++cf) {
            if (!last) {
#pragma unroll
              for (int q = 0; q < 4; ++q) zacc[w][4 * la4 + q][16 * cf + la15] = acc0[cf][q];
            }
            st128f_dev(zb + (16 * cf + la15) * 32 + 4 * la4, accE[cf]);
          }
        }
        // rows 16..31
        {
          f32x4 acc0[2] = {}, accE[2] = {};
#pragma unroll
          for (int j8 = 0; j8 < 8; ++j8) {
#pragma unroll
            for (int cf = 0; cf < 2; ++cf) {
              int zc = 16 * cf + la15;
              int sl = (4 * (ks0 + j8) + la4) ^ (zc & 7);
              int boff = zc * 2048 + (sl << 4);
              if (!last) acc0[cf] = mfma16(aw1[j8], *(const s16x8 *)((const char *)sW + boff), acc0[cf]);
              accE[cf] = mfma16(aw1[j8], *(const s16x8 *)((const char *)sE + boff), accE[cf]);
            }
          }
#pragma unroll
          for (int cf = 0; cf < 2; ++cf) {
            if (!last) {
#pragma unroll
              for (int q = 0; q < 4; ++q) zacc[w][16 + 4 * la4 + q][16 * cf + la15] = acc0[cf][q];
            }
            st128f_dev(zb + (16 * cf + la15) * 32 + 16 + 4 * la4, accE[cf]);
          }
        }
      }
      __syncthreads();
      if (!last) {
        float z4[4];
#pragma unroll
        for (int gi = 0; gi < 4; ++gi) {
          float s = xzv[gi];
          if (t > 0) {
            int zc = gi * 8 + hc;
            s += zacc[0][r_g][zc] + zacc[1][r_g][zc] + zacc[2][r_g][zc] + zacc[3][r_g][zc];
          }
          z4[gi] = s;
        }
        float ig = fsig(z4[0]);
        float fg = fsig(z4[1]);
        float gg = ftanh(z4[2]);
        float og = fsig(z4[3]);
        float c = fg * sC[tid] + ig * gg;
        sC[tid] = c;
        float h = og * ftanh(c);
        st16_dev(h0h + ((size_t)t * 32 + r_g) * HDIM + 8 * g + hc, f2bf(h));
      }
      asm volatile("s_waitcnt vmcnt(0)" ::: "memory");  // h + zeffP stores at L3
      __syncthreads();
      if (tid == 0) st32_dev(flags + g, t + 1);
    }
  } else {
    // ---------------- layer 1 (512 slots, lag 2) ----------------
    float bef[4];
#pragma unroll
    for (int gi = 0; gi < 4; ++gi) bef[gi] = beff[gi * HDIM + 8 * g + hc];
    const int zc2 = tid >> 3, rowq = (tid & 7) << 2;  // zeff gather coords
    for (int t = 0; t < SEQT; ++t) {
      if (w == 0) {
        const int *f0 = flags + lane;
        const int *f1 = flags + 128 + lane;
        const int need0 = t + 2;  // flag0 >= t+2  =>  zeffP[t] complete
        for (long tries = 0;; ++tries) {
          int a = __hip_atomic_load(f0, __ATOMIC_RELAXED, __HIP_MEMORY_SCOPE_AGENT);
          int b = __hip_atomic_load(f0 + 64, __ATOMIC_RELAXED, __HIP_MEMORY_SCOPE_AGENT);
          bool ok = (a >= need0 && b >= need0);
          if (t > 0) {
            int c = __hip_atomic_load(f1, __ATOMIC_RELAXED, __HIP_MEMORY_SCOPE_AGENT);
            int d = __hip_atomic_load(f1 + 64, __ATOMIC_RELAXED, __HIP_MEMORY_SCOPE_AGENT);
            ok = ok && (c >= t && d >= t);
          }
          if (__all(ok)) break;
          if (tries > (1L << 22)) break;  // safety valve
          __builtin_amdgcn_s_sleep(1);
        }
      }
      __syncthreads();
      // issue ALL loads for this step: 16 h1 ld128 (t>0) + 4 zeff f32x4
      s16x8 aw0[8], aw1[8];
      const u16 *pA = h1h + (size_t)(t - 1) * 32 * HDIM;
      if (t > 0) {
#pragma unroll
        for (int j8 = 0; j8 < 8; ++j8)
          aw0[j8] = ld128_dev(pA + (size_t)la15 * HDIM + 32 * (ks0 + j8) + 8 * la4);
#pragma unroll
        for (int j8 = 0; j8 < 8; ++j8)
          aw1[j8] = ld128_dev(pA + (size_t)(16 + la15) * HDIM + 32 * (ks0 + j8) + 8 * la4);
      }
      const float *rb0 = zeffP + (((size_t)(t & 15) * 128 + g) << 12);
      f32x4 zp0 = ldf4_dev(rb0 + zc2 * 32 + rowq);
      f32x4 zp1 = ldf4_dev(rb0 + 1024 + zc2 * 32 + rowq);
      f32x4 zp2 = ldf4_dev(rb0 + 2048 + zc2 * 32 + rowq);
      f32x4 zp3 = ldf4_dev(rb0 + 3072 + zc2 * 32 + rowq);
      asm volatile("s_waitcnt vmcnt(0)" ::: "memory");
      __builtin_amdgcn_sched_barrier(0);  // rule 18: nothing hoists above
      {  // park zeff sums in LDS immediately (no long-lived asm outputs)
        f32x4 s4 = zp0 + zp1 + zp2 + zp3;
        zE[zc2][rowq + 0] = s4[0];
        zE[zc2][rowq + 1] = s4[1];
        zE[zc2][rowq + 2] = s4[2];
        zE[zc2][rowq + 3] = s4[3];
      }
      if (t > 0) {
        {
          f32x4 acc0[2] = {};
#pragma unroll
          for (int j8 = 0; j8 < 8; ++j8) {
#pragma unroll
            for (int cf = 0; cf < 2; ++cf) {
              int zc = 16 * cf + la15;
              int sl = (4 * (ks0 + j8) + la4) ^ (zc & 7);
              int boff = zc * 2048 + (sl << 4);
              acc0[cf] = mfma16(aw0[j8], *(const s16x8 *)((const char *)sW + boff), acc0[cf]);
            }
          }
#pragma unroll
          for (int cf = 0; cf < 2; ++cf)
#pragma unroll
            for (int q = 0; q < 4; ++q) zacc[w][4 * la4 + q][16 * cf + la15] = acc0[cf][q];
        }
        {
          f32x4 acc0[2] = {};
#pragma unroll
          for (int j8 = 0; j8 < 8; ++j8) {
#pragma unroll
            for (int cf = 0; cf < 2; ++cf) {
              int zc = 16 * cf + la15;
              int sl = (4 * (ks0 + j8) + la4) ^ (zc & 7);
              int boff = zc * 2048 + (sl << 4);
              acc0[cf] = mfma16(aw1[j8], *(const s16x8 *)((const char *)sW + boff), acc0[cf]);
            }
          }
#pragma unroll
          for (int cf = 0; cf < 2; ++cf)
#pragma unroll
            for (int q = 0; q < 4; ++q) zacc[w][16 + 4 * la4 + q][16 * cf + la15] = acc0[cf][q];
        }
      }
      __syncthreads();
      {
        float z4[4];
#pragma unroll
        for (int gi = 0; gi < 4; ++gi) {
          int zc = gi * 8 + hc;
          float s = bef[gi] + zE[zc][r_g];
          if (t > 0)
            s += zacc[0][r_g][zc] + zacc[1][r_g][zc] + zacc[2][r_g][zc] + zacc[3][r_g][zc];
          z4[gi] = s;
        }
        float ig = fsig(z4[0]);
        float fg = fsig(z4[1]);
        float gg = ftanh(z4[2]);
        float og = fsig(z4[3]);
        float c = fg * sC[tid] + ig * gg;
        sC[tid] = c;
        float h = og * ftanh(c);
        st16_dev(h1h + ((size_t)t * 32 + r_g) * HDIM + 8 * g + hc, f2bf(h));
      }
      asm volatile("s_waitcnt vmcnt(0)" ::: "memory");
      __syncthreads();
      if (tid == 0) st32_dev(flags + 128 + g, t + 1);
    }
  }
}

// ---------------- host launcher ----------------
extern "C" void kernel_launch(void *const *d_in, const int *in_sizes, int n_in,
                              void *d_out, int out_size, void *d_ws, size_t ws_size,
                              hipStream_t stream) {
  const int *tokens = (const int *)d_in[0];
  const float *embed = (const float *)d_in[1];
  const float *Wx0 = (const float *)d_in[2];
  const float *Wh0 = (const float *)d_in[3];
  const float *b0 = (const float *)d_in[4];
  const float *Wfc0 = (const float *)d_in[5];
  const float *bfc0 = (const float *)d_in[6];
  const float *Wx1 = (const float *)d_in[7];
  const float *Wh1 = (const float *)d_in[8];
  const float *b1 = (const float *)d_in[9];
  const float *Wfc1 = (const float *)d_in[10];
  const float *bfc1 = (const float *)d_in[11];

  constexpr size_t NEED = 255856640;  // ~244 MiB (unchanged from validated R1)
  if (ws_size < NEED) {
    fprintf(stderr, "RNNLM kernel: ws too small (%zu < %zu)\n", ws_size, NEED);
    return;
  }
  char *ws = (char *)d_ws;
  u16 *xz0 = (u16 *)(ws + 0);           // [16384][4096] bf16, rows m=b*T+t
  u16 *h0h = (u16 *)(ws + 134217728);   // h0 hist [512][32][1024] bf16 (32 MB)
  u16 *h1h = (u16 *)(ws + 167772160);   // h1 hist (32 MB)
  u16 *x0hi = (u16 *)(ws + 201326592);  // 16 MB, dead after xz0 GEMM
  u16 *x0lo = (u16 *)(ws + 218103808);  // 16 MB, dead after xz0 GEMM
  // carved into the x0 region AFTER the xz0 GEMM (stream-ordered):
  u16 *Weff = (u16 *)(ws + 201326592);      // [1024][4096] bf16 (8 MB)
  u16 *Wfc0hi = (u16 *)(ws + 209715200);    // [1024][512] (1 MB)
  u16 *Wfc0lo = (u16 *)(ws + 210763776);    // 1 MB
  u16 *WfcT1hi = (u16 *)(ws + 211812352);   // [512][1024] (1 MB)
  u16 *WfcT1lo = (u16 *)(ws + 212860928);   // 1 MB
  float *beff = (float *)(ws + 213909504);  // [4096] f32 (16 KB)
  int *flags = (int *)(ws + 213925888);     // [256] (1 KB)
  // zeffP ring [16][128][4][32][32] f32 = 32 MB. Spans tail of x0 region +
  // WxT0 + WxT1 regions — ALL dead by the coop launch.
  float *zeffP = (float *)(ws + 218103808);
  // own regions (live until their consumer GEMMs):
  u16 *WxT0hi = (u16 *)(ws + 234881024);  // [4096][512] (4 MB)
  u16 *WxT0lo = (u16 *)(ws + 239075328);
  u16 *WxT1hi = (u16 *)(ws + 243269632);  // [4096][512] (4 MB)
  u16 *WxT1lo = (u16 *)(ws + 247463936);  // ends 251658240

  // prepack (regions disjoint from x0)
  k_packT<<<dim3(G4H / 32, DEMB / 32), dim3(32, 8), 0, stream>>>(Wx0, WxT0hi, WxT0lo, DEMB, G4H);
  k_packT<<<dim3(G4H / 32, DEMB / 32), dim3(32, 8), 0, stream>>>(Wx1, WxT1hi, WxT1lo, DEMB, G4H);
  // x0 = embed[tokens] hi/lo
  k_gather_pack<<<4096, 256, 0, stream>>>(tokens, embed, x0hi, x0lo);
  // xz0 = x0 @ Wx0 + b0 -> bf16 (rows m = b*T + t)
  k_gemm<0, 0><<<dim3(128 * 32), 256, 0, stream>>>(x0hi, x0lo, WxT0hi, WxT0lo, b0, xz0,
                                                   16384, G4H, DEMB);
  // x0 now dead: build fused layer-1 input path in its place
  k_split<<<2048, 256, 0, stream>>>(Wfc0, Wfc0hi, Wfc0lo, HDIM * PDIM);
  k_packT<<<dim3(PDIM / 32, HDIM / 32), dim3(32, 8), 0, stream>>>(Wfc1, WfcT1hi, WfcT1lo, HDIM, PDIM);
  k_beff<<<16, 256, 0, stream>>>(bfc0, Wx1, b1, beff);
  (void)hipMemsetAsync(flags, 0, 256 * sizeof(int), stream);
  // Weff = Wfc0 @ Wx1 -> bf16 [1024][4096]  (A=Wfc0 hi/lo, B=WxT1 hi/lo)
  k_gemm<0, 0><<<dim3(8 * 32), 256, 0, stream>>>(Wfc0hi, Wfc0lo, WxT1hi, WxT1lo, nullptr, Weff,
                                                 1024, G4H, PDIM);
  // balanced pipelined both-layer recurrence (one cooperative dispatch)
  {
    const u16 *a0 = xz0; const float *a1 = Wh0; const float *a2 = Wh1;
    const u16 *a3 = Weff; const float *a4 = beff;
    u16 *a5 = h0h; u16 *a6 = h1h; float *a7 = zeffP; int *a8 = flags;
    void *args[] = {&a0, &a1, &a2, &a3, &a4, &a5, &a6, &a7, &a8};
    hipError_t e = hipLaunchCooperativeKernel((void *)k_recur_pipe, dim3(256), dim3(256), args, 0, stream);
    if (e != hipSuccess) fprintf(stderr, "coop launch failed: %d\n", (int)e);
  }
  // out = h1 @ Wfc1 + bfc1 -> f32 scattered to (B,T,P)  (A single bf16)
  k_gemm<2, 1><<<dim3(128 * 4), 256, 0, stream>>>(h1h, h1h, WfcT1hi, WfcT1lo, bfc1, d_out,
                                                  16384, PDIM, HDIM);
}

// Round 10
// 5150.875 us; speedup vs baseline: 1.2706x; 1.0094x over previous
//
#include <hip/hip_runtime.h>
#include <cstdio>
#include <cstdint>

typedef unsigned short u16;
typedef unsigned int u32;
typedef float f32x4 __attribute__((ext_vector_type(4)));
typedef short s16x8 __attribute__((ext_vector_type(8)));
typedef int i32x2 __attribute__((ext_vector_type(2)));

#define DI __device__ __forceinline__

// problem sizes
#define BATCH 32
#define SEQT 512
#define HDIM 1024
#define PDIM 512
#define DEMB 512
#define G4H 4096

// ---------------- bf16 helpers (RNE + hi/lo split) ----------------
DI u16 f2bf(float f) {
  u32 u = __float_as_uint(f);
  return (u16)((u + 0x7fffu + ((u >> 16) & 1u)) >> 16);
}
DI float bf2f(u16 h) { return __uint_as_float(((u32)h) << 16); }
DI void split2(float f, u16 &hi, u16 &lo) {
  hi = f2bf(f);
  lo = f2bf(f - bf2f(hi));  // exact residual capture to ~2^-17 rel
}
DI f32x4 mfma16(s16x8 a, s16x8 b, f32x4 c) {
  return __builtin_amdgcn_mfma_f32_16x16x32_bf16(a, b, c, 0, 0, 0);
}
DI void dma16(const void *g, void *l) {
  __builtin_amdgcn_global_load_lds((const __attribute__((address_space(1))) void *)g,
                                   (__attribute__((address_space(3))) void *)l, 16, 0, 0);
}
// device-scope (sc1) ops: bypass L1/L2, talk straight to the coherence point.
// Zero cache-maintenance instructions anywhere in the recurrence handshake.
// RULE-18/20 DISCIPLINE (R8 lesson): every asm-load's output is consumed or
// converted to normal values IMMEDIATELY after vmcnt(0)+sched_barrier(0).
DI s16x8 ld128_dev(const u16 *p) {
  s16x8 r;
  asm volatile("global_load_dwordx4 %0, %1, off sc1" : "=v"(r) : "v"(p));
  return r;
}
DI i32x2 ld64_dev(const u16 *p) {
  i32x2 r;
  asm volatile("global_load_dwordx2 %0, %1, off sc1" : "=v"(r) : "v"(p));
  return r;
}
DI void st16_dev(u16 *p, u16 v) {
  asm volatile("global_store_short %0, %1, off sc1" ::"v"(p), "v"((u32)v) : "memory");
}
DI void st32_dev(int *p, int v) {
  asm volatile("global_store_dword %0, %1, off sc1" ::"v"(p), "v"(v) : "memory");
}
DI void st64_dev(u16 *p, i32x2 v) {
  asm volatile("global_store_dwordx2 %0, %1, off sc1" ::"v"(p), "v"(v) : "memory");
}

// fast gate math: hardware exp2 + rcp (~1e-7 abs err on sigmoid/tanh outputs)
#if __has_builtin(__builtin_amdgcn_exp2f) && __has_builtin(__builtin_amdgcn_rcpf)
DI float fsig(float x) {
  return __builtin_amdgcn_rcpf(1.f + __builtin_amdgcn_exp2f(-1.4426950408889634f * x));
}
DI float ftanh(float x) {
  return 2.f * __builtin_amdgcn_rcpf(1.f + __builtin_amdgcn_exp2f(-2.8853900817779268f * x)) - 1.f;
}
#else
DI float fsig(float x) { return 1.f / (1.f + expf(-x)); }
DI float ftanh(float x) { return tanhf(x); }
#endif

// ---------------- embed gather -> x0 hi/lo planes ----------------
__global__ void k_gather_pack(const int *__restrict__ tokens, const float *__restrict__ embed,
                              u16 *__restrict__ xhi, u16 *__restrict__ xlo) {
  int idx = blockIdx.x * 256 + threadIdx.x;  // one thread per 8 elements
  int m = idx >> 6;                          // row 0..16383 (m = b*T + t)
  int k8 = (idx & 63) << 3;
  int tok = tokens[m];
  const float *src = embed + (size_t)tok * DEMB + k8;
  float4 a = *(const float4 *)src;
  float4 b = *(const float4 *)(src + 4);
  float v[8] = {a.x, a.y, a.z, a.w, b.x, b.y, b.z, b.w};
  union UV { u16 h[8]; int4 v; };
  UV uh, ul;
#pragma unroll
  for (int j = 0; j < 8; ++j) split2(v[j], uh.h[j], ul.h[j]);
  size_t o = (size_t)m * DEMB + k8;
  *(int4 *)(xhi + o) = uh.v;
  *(int4 *)(xlo + o) = ul.v;
}

// ------- transpose+split weights: W[K][N] f32 -> T[N][K] bf16 hi/lo -------
__global__ void k_packT(const float *__restrict__ W, u16 *__restrict__ Thi, u16 *__restrict__ Tlo,
                        int K, int N) {
  __shared__ float tile[32][33];
  int n0 = blockIdx.x * 32, k0 = blockIdx.y * 32;
  int tx = threadIdx.x, ty = threadIdx.y;  // (32,8)
#pragma unroll
  for (int i = 0; i < 4; ++i) tile[ty + 8 * i][tx] = W[(size_t)(k0 + ty + 8 * i) * N + n0 + tx];
  __syncthreads();
#pragma unroll
  for (int i = 0; i < 4; ++i) {
    int n = ty + 8 * i;
    u16 hi, lo;
    split2(tile[tx][n], hi, lo);
    size_t o = (size_t)(n0 + n) * K + k0 + tx;
    Thi[o] = hi;
    Tlo[o] = lo;
  }
}

// ------- elementwise hi/lo split (row-major, no transpose) -------
__global__ void k_split(const float *__restrict__ W, u16 *__restrict__ hi, u16 *__restrict__ lo,
                        int n) {
  int i = blockIdx.x * 256 + threadIdx.x;
  if (i < n) split2(W[i], hi[i], lo[i]);
}

// ------- beff = bfc0 @ Wx1 + b1  (f32 [4096]) -------
__global__ void k_beff(const float *__restrict__ bfc0, const float *__restrict__ Wx1,
                       const float *__restrict__ b1, float *__restrict__ beff) {
  int n = blockIdx.x * 256 + threadIdx.x;  // 4096
  float acc = b1[n];
  for (int j = 0; j < PDIM; ++j) acc += bfc0[j] * Wx1[(size_t)j * G4H + n];
  beff[n] = acc;
}

// ---------------- generic bf16x3 GEMM ----------------
// C[M][N] = A[M][K] * B^T-source[N][K] + bias, A/B given as bf16 hi/lo planes.
// OM: 0 = bf16 out, 2 = f32 out scattered to (B,T,P).
// SA: 1 = A is single bf16 (Alo ignored; plane 1 zero-filled once).
template <int OM, int SA>
__global__ __launch_bounds__(256, 2) void k_gemm(const u16 *__restrict__ Ahi, const u16 *__restrict__ Alo,
                                                 const u16 *__restrict__ Bhi, const u16 *__restrict__ Blo,
                                                 const float *__restrict__ bias, void *__restrict__ out0,
                                                 int M, int N, int K) {
  __shared__ u16 sP[4][128 * 64];  // planes: Ahi, Alo, Bhi, Blo (16KB each)
  const int tid = threadIdx.x;
  const int w = tid >> 6, lane = tid & 63;
  const int la15 = lane & 15, la4 = lane >> 4;
  const int nbn = N >> 7;
  const int bm = blockIdx.x / nbn, bn = blockIdx.x % nbn;
  const u16 *src = (w == 0) ? Ahi : (w == 1) ? Alo : (w == 2) ? Bhi : Blo;
  const int rowbase = (w < 2) ? bm * 128 : bn * 128;
  char *lds = (char *)&sP[w][0];

  if (SA) {  // zero the Alo plane once; its MFMAs then contribute +0
    for (int i = tid; i < 2048; i += 256) ((unsigned long long *)&sP[1][0])[i] = 0ULL;
  }

  f32x4 acc[2][8] = {};
  for (int kb = 0; kb < K; kb += 64) {
    if (!(SA && w == 1)) {
#pragma unroll
      for (int i = 0; i < 16; ++i) {
        int s = i * 64 + lane;            // 16B slot id
        int row = s >> 3;                 // 8 slots per 128B row
        int k16 = (s & 7) ^ (row & 7);    // inverse of read swizzle
        dma16(src + (size_t)(rowbase + row) * K + kb + k16 * 8, lds + i * 1024);
      }
    }
    asm volatile("s_waitcnt vmcnt(0)" ::: "memory");
    __syncthreads();
#pragma unroll
    for (int ksl = 0; ksl < 2; ++ksl) {
      s16x8 ah[2], al[2];
#pragma unroll
      for (int rf = 0; rf < 2; ++rf) {
        int row = 32 * w + 16 * rf + la15;
        int slot = row * 8 + ((4 * ksl + la4) ^ (row & 7));
        ah[rf] = *(const s16x8 *)((const char *)&sP[0][0] + slot * 16);
        al[rf] = *(const s16x8 *)((const char *)&sP[1][0] + slot * 16);
      }
#pragma unroll
      for (int cf = 0; cf < 8; ++cf) {
        int col = 16 * cf + la15;
        int slot = col * 8 + ((4 * ksl + la4) ^ (col & 7));
        s16x8 bh = *(const s16x8 *)((const char *)&sP[2][0] + slot * 16);
        s16x8 bl = *(const s16x8 *)((const char *)&sP[3][0] + slot * 16);
#pragma unroll
        for (int rf = 0; rf < 2; ++rf) {
          acc[rf][cf] = mfma16(ah[rf], bh, acc[rf][cf]);
          acc[rf][cf] = mfma16(ah[rf], bl, acc[rf][cf]);
          acc[rf][cf] = mfma16(al[rf], bh, acc[rf][cf]);
        }
      }
    }
    __syncthreads();
  }
  // epilogue: D[r][c], r = 4*(lane>>4)+q (M), c = lane&15 (N)  [m89-verified]
#pragma unroll
  for (int rf = 0; rf < 2; ++rf) {
#pragma unroll
    for (int cf = 0; cf < 8; ++cf) {
      int c = bn * 128 + 16 * cf + la15;
      float bv = bias ? bias[c] : 0.f;
#pragma unroll
      for (int q = 0; q < 4; ++q) {
        int r = bm * 128 + 32 * w + 16 * rf + 4 * la4 + q;
        float v = acc[rf][cf][q] + bv;
        if (OM == 0) {
          ((u16 *)out0)[(size_t)r * N + c] = f2bf(v);
        } else {
          int b2 = r & 31, tt = r >> 5;  // A rows are m = t*32 + b
          ((float *)out0)[((size_t)b2 * SEQT + tt) * PDIM + c] = v;
        }
      }
    }
  }
}

// ---------------- pipelined 2-layer persistent LSTM recurrence (R10) ----------------
// Same pipe as R9 (L0 computes zeff for L1 off shared A-regs) but the ring is
// REDUCED + bf16 + COALESCED (R9's sin: 2 MB/step unreduced f32 partials as
// partial-line sc1 writes -> 1.18 GB HBM writeback, slow pre-flag drains).
// L0 reuses zacc for a 2nd reduction phase (accE), then thread (row,hc) packs
// its 4 gate-values into ONE 8 B dwordx2 -> ring slice is 2 KB/WG contiguous.
// L1 loads its 8 B back (same thread owns the same (row,hc,gi) it gates) ->
// unpacked to normal floats right after vmcnt (no long-lived asm outputs).
// Ring: zeffR[16][128][32*8*4] bf16 = 4 MB. Flags/lags identical to R9.
__global__ __launch_bounds__(256, 1) void k_recur_pipe(
    const u16 *__restrict__ xz0, const float *__restrict__ Wh0, const float *__restrict__ Wh1,
    const u16 *__restrict__ Weff, const float *__restrict__ beff,
    u16 *h0h, u16 *h1h, u16 *zeffR, int *flags) {
  __shared__ u16 sW[32 * 1024];      // 64 KB: layer's Wh slice [zc][k] swizzled
  __shared__ u16 sE[32 * 1024];      // 64 KB: L0's Weff slice (unused by L1)
  __shared__ float zacc[4][32][33];  // per-wave K-partials (+1 col pad), 2-phase reuse
  __shared__ float sC[256];          // cell state c[32 rows][8 cols]
  const int tid = threadIdx.x;
  const int w = tid >> 6, lane = tid & 63;
  const int la15 = lane & 15, la4 = lane >> 4;
  const int wg = blockIdx.x;
  const int layer = wg >> 7;
  const int g = wg & 127;  // 8 h-cols: [8g, 8g+8)

  // stage weights (single bf16, swizzled), once per launch
  const float *Wh = layer ? Wh1 : Wh0;
  for (int i2 = tid; i2 < 32 * 1024; i2 += 256) {
    int zc = i2 & 31;
    int k = i2 >> 5;
    int gcol = (zc >> 3) * HDIM + 8 * g + (zc & 7);
    int boff = zc * 2048 + ((((k >> 3) ^ (zc & 7))) << 4) + (k & 7) * 2;
    *(u16 *)((char *)sW + boff) = f2bf(Wh[(size_t)k * G4H + gcol]);
    if (!layer) *(u16 *)((char *)sE + boff) = Weff[(size_t)k * G4H + gcol];
  }
  sC[tid] = 0.f;
  __syncthreads();

  const int r_g = tid >> 3, hc = tid & 7;  // gate coords: 32 rows x 8 cols
  const int ks0 = 8 * w;                   // wave's k-slice (256 k)

  if (!layer) {
    // ---------------- layer 0 (513 slots) ----------------
    for (int t = 0; t <= SEQT; ++t) {
      const bool last = (t == SEQT);
      float xzv[4] = {0.f, 0.f, 0.f, 0.f};
      if (!last) {
        const u16 *px = xz0 + ((size_t)r_g * SEQT + t) * G4H + 8 * g + hc;
#pragma unroll
        for (int gi = 0; gi < 4; ++gi) xzv[gi] = bf2f(px[(size_t)gi * HDIM]);
      }
      if (w == 0 && t > 0) {
        const int *f0 = flags + lane;
        const int *f1 = flags + 128 + lane;
        const int bp = t - 16;
        for (long tries = 0;; ++tries) {
          int a = __hip_atomic_load(f0, __ATOMIC_RELAXED, __HIP_MEMORY_SCOPE_AGENT);
          int b = __hip_atomic_load(f0 + 64, __ATOMIC_RELAXED, __HIP_MEMORY_SCOPE_AGENT);
          bool ok = (a >= t && b >= t);
          if (t > 16) {  // ring back-pressure (slot reuse after 16 steps)
            int c = __hip_atomic_load(f1, __ATOMIC_RELAXED, __HIP_MEMORY_SCOPE_AGENT);
            int d = __hip_atomic_load(f1 + 64, __ATOMIC_RELAXED, __HIP_MEMORY_SCOPE_AGENT);
            ok = ok && (c >= bp && d >= bp);
          }
          if (__all(ok)) break;
          if (tries > (1L << 22)) break;  // safety valve
          __builtin_amdgcn_s_sleep(1);
        }
      }
      __syncthreads();
      f32x4 accE[2][2] = {};  // [rt][cf], survives to the reduce phase
      if (t > 0) {
        const u16 *pA = h0h + (size_t)(t - 1) * 32 * HDIM;
        // issue ALL 16 A-loads (both row halves), then one vmcnt
        s16x8 aw0[8], aw1[8];
#pragma unroll
        for (int j8 = 0; j8 < 8; ++j8)
          aw0[j8] = ld128_dev(pA + (size_t)la15 * HDIM + 32 * (ks0 + j8) + 8 * la4);
#pragma unroll
        for (int j8 = 0; j8 < 8; ++j8)
          aw1[j8] = ld128_dev(pA + (size_t)(16 + la15) * HDIM + 32 * (ks0 + j8) + 8 * la4);
        asm volatile("s_waitcnt vmcnt(0)" ::: "memory");
        __builtin_amdgcn_sched_barrier(0);  // rule 18
        {
          f32x4 acc0[2] = {};
#pragma unroll
          for (int j8 = 0; j8 < 8; ++j8) {
#pragma unroll
            for (int cf = 0; cf < 2; ++cf) {
              int zc = 16 * cf + la15;
              int sl = (4 * (ks0 + j8) + la4) ^ (zc & 7);
              int boff = zc * 2048 + (sl << 4);
              if (!last) acc0[cf] = mfma16(aw0[j8], *(const s16x8 *)((const char *)sW + boff), acc0[cf]);
              accE[0][cf] = mfma16(aw0[j8], *(const s16x8 *)((const char *)sE + boff), accE[0][cf]);
            }
          }
          if (!last) {
#pragma unroll
            for (int cf = 0; cf < 2; ++cf)
#pragma unroll
              for (int q = 0; q < 4; ++q) zacc[w][4 * la4 + q][16 * cf + la15] = acc0[cf][q];
          }
        }
        {
          f32x4 acc0[2] = {};
#pragma unroll
          for (int j8 = 0; j8 < 8; ++j8) {
#pragma unroll
            for (int cf = 0; cf < 2; ++cf) {
              int zc = 16 * cf + la15;
              int sl = (4 * (ks0 + j8) + la4) ^ (zc & 7);
              int boff = zc * 2048 + (sl << 4);
              if (!last) acc0[cf] = mfma16(aw1[j8], *(const s16x8 *)((const char *)sW + boff), acc0[cf]);
              accE[1][cf] = mfma16(aw1[j8], *(const s16x8 *)((const char *)sE + boff), accE[1][cf]);
            }
          }
          if (!last) {
#pragma unroll
            for (int cf = 0; cf < 2; ++cf)
#pragma unroll
              for (int q = 0; q < 4; ++q) zacc[w][16 + 4 * la4 + q][16 * cf + la15] = acc0[cf][q];
          }
        }
      }
      __syncthreads();  // zacc(acc0) ready for gates
      if (!last) {
        float z4[4];
#pragma unroll
        for (int gi = 0; gi < 4; ++gi) {
          float s = xzv[gi];
          if (t > 0) {
            int zc = gi * 8 + hc;
            s += zacc[0][r_g][zc] + zacc[1][r_g][zc] + zacc[2][r_g][zc] + zacc[3][r_g][zc];
          }
          z4[gi] = s;
        }
        float ig = fsig(z4[0]);
        float fg = fsig(z4[1]);
        float gg = ftanh(z4[2]);
        float og = fsig(z4[3]);
        float c = fg * sC[tid] + ig * gg;
        sC[tid] = c;
        float h = og * ftanh(c);
        st16_dev(h0h + ((size_t)t * 32 + r_g) * HDIM + 8 * g + hc, f2bf(h));
      }
      __syncthreads();  // gates' zacc reads complete -> safe to overwrite
      if (t > 0) {
        // phase 2: zacc <- accE
#pragma unroll
        for (int rt = 0; rt < 2; ++rt)
#pragma unroll
          for (int cf = 0; cf < 2; ++cf)
#pragma unroll
            for (int q = 0; q < 4; ++q)
              zacc[w][16 * rt + 4 * la4 + q][16 * cf + la15] = accE[rt][cf][q];
      }
      __syncthreads();  // zacc(accE) ready
      if (t > 0) {
        // reduce across waves + pack 4 bf16 -> one coalesced 8B store
        float ze[4];
#pragma unroll
        for (int gi = 0; gi < 4; ++gi) {
          int zc = gi * 8 + hc;
          ze[gi] = zacc[0][r_g][zc] + zacc[1][r_g][zc] + zacc[2][r_g][zc] + zacc[3][r_g][zc];
        }
        i32x2 pk;
        pk[0] = (int)(((u32)f2bf(ze[1]) << 16) | (u32)f2bf(ze[0]));
        pk[1] = (int)(((u32)f2bf(ze[3]) << 16) | (u32)f2bf(ze[2]));
        st64_dev(zeffR + (((size_t)((t - 1) & 15) * 128 + g) << 10) + tid * 4, pk);
      }
      asm volatile("s_waitcnt vmcnt(0)" ::: "memory");  // h + zeff stores at L3
      __syncthreads();
      if (tid == 0) st32_dev(flags + g, t + 1);
    }
  } else {
    // ---------------- layer 1 (512 slots, lag 2) ----------------
    float bef[4];
#pragma unroll
    for (int gi = 0; gi < 4; ++gi) bef[gi] = beff[gi * HDIM + 8 * g + hc];
    for (int t = 0; t < SEQT; ++t) {
      if (w == 0) {
        const int *f0 = flags + lane;
        const int *f1 = flags + 128 + lane;
        const int need0 = t + 2;  // flag0 >= t+2  =>  zeff[t] complete
        for (long tries = 0;; ++tries) {
          int a = __hip_atomic_load(f0, __ATOMIC_RELAXED, __HIP_MEMORY_SCOPE_AGENT);
          int b = __hip_atomic_load(f0 + 64, __ATOMIC_RELAXED, __HIP_MEMORY_SCOPE_AGENT);
          bool ok = (a >= need0 && b >= need0);
          if (t > 0) {
            int c = __hip_atomic_load(f1, __ATOMIC_RELAXED, __HIP_MEMORY_SCOPE_AGENT);
            int d = __hip_atomic_load(f1 + 64, __ATOMIC_RELAXED, __HIP_MEMORY_SCOPE_AGENT);
            ok = ok && (c >= t && d >= t);
          }
          if (__all(ok)) break;
          if (tries > (1L << 22)) break;  // safety valve
          __builtin_amdgcn_s_sleep(1);
        }
      }
      __syncthreads();
      // issue ALL loads: 16 h1 ld128 (t>0) + this thread's 8B zeff chunk
      s16x8 aw0[8], aw1[8];
      const u16 *pA = h1h + (size_t)(t - 1) * 32 * HDIM;
      if (t > 0) {
#pragma unroll
        for (int j8 = 0; j8 < 8; ++j8)
          aw0[j8] = ld128_dev(pA + (size_t)la15 * HDIM + 32 * (ks0 + j8) + 8 * la4);
#pragma unroll
        for (int j8 = 0; j8 < 8; ++j8)
          aw1[j8] = ld128_dev(pA + (size_t)(16 + la15) * HDIM + 32 * (ks0 + j8) + 8 * la4);
      }
      i32x2 zpk = ld64_dev(zeffR + (((size_t)(t & 15) * 128 + g) << 10) + tid * 4);
      asm volatile("s_waitcnt vmcnt(0)" ::: "memory");
      __builtin_amdgcn_sched_barrier(0);  // rule 18
      // convert asm outputs to normal values NOW (spill-safe thereafter)
      float zv[4];
      zv[0] = bf2f((u16)((u32)zpk[0] & 0xffffu));
      zv[1] = bf2f((u16)((u32)zpk[0] >> 16));
      zv[2] = bf2f((u16)((u32)zpk[1] & 0xffffu));
      zv[3] = bf2f((u16)((u32)zpk[1] >> 16));
      if (t > 0) {
        {
          f32x4 acc0[2] = {};
#pragma unroll
          for (int j8 = 0; j8 < 8; ++j8) {
#pragma unroll
            for (int cf = 0; cf < 2; ++cf) {
              int zc = 16 * cf + la15;
              int sl = (4 * (ks0 + j8) + la4) ^ (zc & 7);
              int boff = zc * 2048 + (sl << 4);
              acc0[cf] = mfma16(aw0[j8], *(const s16x8 *)((const char *)sW + boff), acc0[cf]);
            }
          }
#pragma unroll
          for (int cf = 0; cf < 2; ++cf)
#pragma unroll
            for (int q = 0; q < 4; ++q) zacc[w][4 * la4 + q][16 * cf + la15] = acc0[cf][q];
        }
        {
          f32x4 acc0[2] = {};
#pragma unroll
          for (int j8 = 0; j8 < 8; ++j8) {
#pragma unroll
            for (int cf = 0; cf < 2; ++cf) {
              int zc = 16 * cf + la15;
              int sl = (4 * (ks0 + j8) + la4) ^ (zc & 7);
              int boff = zc * 2048 + (sl << 4);
              acc0[cf] = mfma16(aw1[j8], *(const s16x8 *)((const char *)sW + boff), acc0[cf]);
            }
          }
#pragma unroll
          for (int cf = 0; cf < 2; ++cf)
#pragma unroll
            for (int q = 0; q < 4; ++q) zacc[w][16 + 4 * la4 + q][16 * cf + la15] = acc0[cf][q];
        }
      }
      __syncthreads();
      {
        float z4[4];
#pragma unroll
        for (int gi = 0; gi < 4; ++gi) {
          float s = bef[gi] + zv[gi];
          if (t > 0) {
            int zc = gi * 8 + hc;
            s += zacc[0][r_g][zc] + zacc[1][r_g][zc] + zacc[2][r_g][zc] + zacc[3][r_g][zc];
          }
          z4[gi] = s;
        }
        float ig = fsig(z4[0]);
        float fg = fsig(z4[1]);
        float gg = ftanh(z4[2]);
        float og = fsig(z4[3]);
        float c = fg * sC[tid] + ig * gg;
        sC[tid] = c;
        float h = og * ftanh(c);
        st16_dev(h1h + ((size_t)t * 32 + r_g) * HDIM + 8 * g + hc, f2bf(h));
      }
      asm volatile("s_waitcnt vmcnt(0)" ::: "memory");
      __syncthreads();
      if (tid == 0) st32_dev(flags + 128 + g, t + 1);
    }
  }
}

// ---------------- host launcher ----------------
extern "C" void kernel_launch(void *const *d_in, const int *in_sizes, int n_in,
                              void *d_out, int out_size, void *d_ws, size_t ws_size,
                              hipStream_t stream) {
  const int *tokens = (const int *)d_in[0];
  const float *embed = (const float *)d_in[1];
  const float *Wx0 = (const float *)d_in[2];
  const float *Wh0 = (const float *)d_in[3];
  const float *b0 = (const float *)d_in[4];
  const float *Wfc0 = (const float *)d_in[5];
  const float *bfc0 = (const float *)d_in[6];
  const float *Wx1 = (const float *)d_in[7];
  const float *Wh1 = (const float *)d_in[8];
  const float *b1 = (const float *)d_in[9];
  const float *Wfc1 = (const float *)d_in[10];
  const float *bfc1 = (const float *)d_in[11];

  constexpr size_t NEED = 255856640;  // ~244 MiB (unchanged from validated R1)
  if (ws_size < NEED) {
    fprintf(stderr, "RNNLM kernel: ws too small (%zu < %zu)\n", ws_size, NEED);
    return;
  }
  char *ws = (char *)d_ws;
  u16 *xz0 = (u16 *)(ws + 0);           // [16384][4096] bf16, rows m=b*T+t
  u16 *h0h = (u16 *)(ws + 134217728);   // h0 hist [512][32][1024] bf16 (32 MB)
  u16 *h1h = (u16 *)(ws + 167772160);   // h1 hist (32 MB)
  u16 *x0hi = (u16 *)(ws + 201326592);  // 16 MB, dead after xz0 GEMM
  u16 *x0lo = (u16 *)(ws + 218103808);  // 16 MB, dead after xz0 GEMM
  // carved into the x0 region AFTER the xz0 GEMM (stream-ordered):
  u16 *Weff = (u16 *)(ws + 201326592);      // [1024][4096] bf16 (8 MB)
  u16 *Wfc0hi = (u16 *)(ws + 209715200);    // [1024][512] (1 MB)
  u16 *Wfc0lo = (u16 *)(ws + 210763776);    // 1 MB
  u16 *WfcT1hi = (u16 *)(ws + 211812352);   // [512][1024] (1 MB)
  u16 *WfcT1lo = (u16 *)(ws + 212860928);   // 1 MB
  float *beff = (float *)(ws + 213909504);  // [4096] f32 (16 KB)
  int *flags = (int *)(ws + 213925888);     // [256] (1 KB)
  // zeffR ring [16][128][1024] bf16 = 4 MB, in the dead x0lo region.
  u16 *zeffR = (u16 *)(ws + 218103808);
  // own regions (live until their consumer GEMMs):
  u16 *WxT0hi = (u16 *)(ws + 234881024);  // [4096][512] (4 MB)
  u16 *WxT0lo = (u16 *)(ws + 239075328);
  u16 *WxT1hi = (u16 *)(ws + 243269632);  // [4096][512] (4 MB)
  u16 *WxT1lo = (u16 *)(ws + 247463936);  // ends 251658240

  // prepack (regions disjoint from x0)
  k_packT<<<dim3(G4H / 32, DEMB / 32), dim3(32, 8), 0, stream>>>(Wx0, WxT0hi, WxT0lo, DEMB, G4H);
  k_packT<<<dim3(G4H / 32, DEMB / 32), dim3(32, 8), 0, stream>>>(Wx1, WxT1hi, WxT1lo, DEMB, G4H);
  // x0 = embed[tokens] hi/lo
  k_gather_pack<<<4096, 256, 0, stream>>>(tokens, embed, x0hi, x0lo);
  // xz0 = x0 @ Wx0 + b0 -> bf16 (rows m = b*T + t)
  k_gemm<0, 0><<<dim3(128 * 32), 256, 0, stream>>>(x0hi, x0lo, WxT0hi, WxT0lo, b0, xz0,
                                                   16384, G4H, DEMB);
  // x0 now dead: build fused layer-1 input path in its place
  k_split<<<2048, 256, 0, stream>>>(Wfc0, Wfc0hi, Wfc0lo, HDIM * PDIM);
  k_packT<<<dim3(PDIM / 32, HDIM / 32), dim3(32, 8), 0, stream>>>(Wfc1, WfcT1hi, WfcT1lo, HDIM, PDIM);
  k_beff<<<16, 256, 0, stream>>>(bfc0, Wx1, b1, beff);
  (void)hipMemsetAsync(flags, 0, 256 * sizeof(int), stream);
  // Weff = Wfc0 @ Wx1 -> bf16 [1024][4096]  (A=Wfc0 hi/lo, B=WxT1 hi/lo)
  k_gemm<0, 0><<<dim3(8 * 32), 256, 0, stream>>>(Wfc0hi, Wfc0lo, WxT1hi, WxT1lo, nullptr, Weff,
                                                 1024, G4H, PDIM);
  // balanced pipelined both-layer recurrence (one cooperative dispatch)
  {
    const u16 *a0 = xz0; const float *a1 = Wh0; const float *a2 = Wh1;
    const u16 *a3 = Weff; const float *a4 = beff;
    u16 *a5 = h0h; u16 *a6 = h1h; u16 *a7 = zeffR; int *a8 = flags;
    void *args[] = {&a0, &a1, &a2, &a3, &a4, &a5, &a6, &a7, &a8};
    hipError_t e = hipLaunchCooperativeKernel((void *)k_recur_pipe, dim3(256), dim3(256), args, 0, stream);
    if (e != hipSuccess) fprintf(stderr, "coop launch failed: %d\n", (int)e);
  }
  // out = h1 @ Wfc1 + bfc1 -> f32 scattered to (B,T,P)  (A single bf16)
  k_gemm<2, 1><<<dim3(128 * 4), 256, 0, stream>>>(h1h, h1h, WfcT1hi, WfcT1lo, bfc1, d_out,
                                                  16384, PDIM, HDIM);
}

// Round 11
// 4915.730 us; speedup vs baseline: 1.3314x; 1.0478x over previous
//
#include <hip/hip_runtime.h>
#include <cstdio>
#include <cstdint>

typedef unsigned short u16;
typedef unsigned int u32;
typedef float f32x4 __attribute__((ext_vector_type(4)));
typedef short s16x8 __attribute__((ext_vector_type(8)));
typedef int i32x2 __attribute__((ext_vector_type(2)));

#define DI __device__ __forceinline__

// problem sizes
#define BATCH 32
#define SEQT 512
#define HDIM 1024
#define PDIM 512
#define DEMB 512
#define G4H 4096

// ---------------- bf16 helpers (RNE + hi/lo split) ----------------
DI u16 f2bf(float f) {
  u32 u = __float_as_uint(f);
  return (u16)((u + 0x7fffu + ((u >> 16) & 1u)) >> 16);
}
DI float bf2f(u16 h) { return __uint_as_float(((u32)h) << 16); }
DI void split2(float f, u16 &hi, u16 &lo) {
  hi = f2bf(f);
  lo = f2bf(f - bf2f(hi));  // exact residual capture to ~2^-17 rel
}
DI f32x4 mfma16(s16x8 a, s16x8 b, f32x4 c) {
  return __builtin_amdgcn_mfma_f32_16x16x32_bf16(a, b, c, 0, 0, 0);
}
DI void dma16(const void *g, void *l) {
  __builtin_amdgcn_global_load_lds((const __attribute__((address_space(1))) void *)g,
                                   (__attribute__((address_space(3))) void *)l, 16, 0, 0);
}
// device-scope (sc1) ops: bypass L1/L2, talk straight to the coherence point.
// RULE-18/20 DISCIPLINE: asm-load outputs consumed right after vmcnt(0)+
// sched_barrier(0); loads->vmcnt gap holds no heavy code.
DI s16x8 ld128_dev(const u16 *p) {
  s16x8 r;
  asm volatile("global_load_dwordx4 %0, %1, off sc1" : "=v"(r) : "v"(p));
  return r;
}
DI i32x2 ld64_dev(const u16 *p) {
  i32x2 r;
  asm volatile("global_load_dwordx2 %0, %1, off sc1" : "=v"(r) : "v"(p));
  return r;
}
DI void st16_dev(u16 *p, u16 v) {
  asm volatile("global_store_short %0, %1, off sc1" ::"v"(p), "v"((u32)v) : "memory");
}
DI void st32_dev(int *p, int v) {
  asm volatile("global_store_dword %0, %1, off sc1" ::"v"(p), "v"(v) : "memory");
}
DI void st64_dev(u16 *p, i32x2 v) {
  asm volatile("global_store_dwordx2 %0, %1, off sc1" ::"v"(p), "v"(v) : "memory");
}
// sentinel detector: any bf16 lane == 0xFFFF (unreachable from f2bf(finite))
DI u32 sentq(s16x8 v) {
  union U { s16x8 s; u32 d[4]; } u;
  u.s = v;
  u32 b = 0;
#pragma unroll
  for (int i = 0; i < 4; ++i)
    b |= (u32)(((u.d[i] & 0xffffu) == 0xffffu) || ((u.d[i] >> 16) == 0xffffu));
  return b;
}

// fast gate math: hardware exp2 + rcp (~1e-7 abs err on sigmoid/tanh outputs)
#if __has_builtin(__builtin_amdgcn_exp2f) && __has_builtin(__builtin_amdgcn_rcpf)
DI float fsig(float x) {
  return __builtin_amdgcn_rcpf(1.f + __builtin_amdgcn_exp2f(-1.4426950408889634f * x));
}
DI float ftanh(float x) {
  return 2.f * __builtin_amdgcn_rcpf(1.f + __builtin_amdgcn_exp2f(-2.8853900817779268f * x)) - 1.f;
}
#else
DI float fsig(float x) { return 1.f / (1.f + expf(-x)); }
DI float ftanh(float x) { return tanhf(x); }
#endif

// ---------------- embed gather -> x0 hi/lo planes ----------------
__global__ void k_gather_pack(const int *__restrict__ tokens, const float *__restrict__ embed,
                              u16 *__restrict__ xhi, u16 *__restrict__ xlo) {
  int idx = blockIdx.x * 256 + threadIdx.x;  // one thread per 8 elements
  int m = idx >> 6;                          // row 0..16383 (m = b*T + t)
  int k8 = (idx & 63) << 3;
  int tok = tokens[m];
  const float *src = embed + (size_t)tok * DEMB + k8;
  float4 a = *(const float4 *)src;
  float4 b = *(const float4 *)(src + 4);
  float v[8] = {a.x, a.y, a.z, a.w, b.x, b.y, b.z, b.w};
  union UV { u16 h[8]; int4 v; };
  UV uh, ul;
#pragma unroll
  for (int j = 0; j < 8; ++j) split2(v[j], uh.h[j], ul.h[j]);
  size_t o = (size_t)m * DEMB + k8;
  *(int4 *)(xhi + o) = uh.v;
  *(int4 *)(xlo + o) = ul.v;
}

// ------- transpose+split weights: W[K][N] f32 -> T[N][K] bf16 hi/lo -------
__global__ void k_packT(const float *__restrict__ W, u16 *__restrict__ Thi, u16 *__restrict__ Tlo,
                        int K, int N) {
  __shared__ float tile[32][33];
  int n0 = blockIdx.x * 32, k0 = blockIdx.y * 32;
  int tx = threadIdx.x, ty = threadIdx.y;  // (32,8)
#pragma unroll
  for (int i = 0; i < 4; ++i) tile[ty + 8 * i][tx] = W[(size_t)(k0 + ty + 8 * i) * N + n0 + tx];
  __syncthreads();
#pragma unroll
  for (int i = 0; i < 4; ++i) {
    int n = ty + 8 * i;
    u16 hi, lo;
    split2(tile[tx][n], hi, lo);
    size_t o = (size_t)(n0 + n) * K + k0 + tx;
    Thi[o] = hi;
    Tlo[o] = lo;
  }
}

// ------- elementwise hi/lo split (row-major, no transpose) -------
__global__ void k_split(const float *__restrict__ W, u16 *__restrict__ hi, u16 *__restrict__ lo,
                        int n) {
  int i = blockIdx.x * 256 + threadIdx.x;
  if (i < n) split2(W[i], hi[i], lo[i]);
}

// ------- beff = bfc0 @ Wx1 + b1  (f32 [4096]) -------
__global__ void k_beff(const float *__restrict__ bfc0, const float *__restrict__ Wx1,
                       const float *__restrict__ b1, float *__restrict__ beff) {
  int n = blockIdx.x * 256 + threadIdx.x;  // 4096
  float acc = b1[n];
  for (int j = 0; j < PDIM; ++j) acc += bfc0[j] * Wx1[(size_t)j * G4H + n];
  beff[n] = acc;
}

// ---------------- generic bf16x3 GEMM ----------------
// C[M][N] = A[M][K] * B^T-source[N][K] + bias, A/B given as bf16 hi/lo planes.
// OM: 0 = bf16 out, 2 = f32 out scattered to (B,T,P).
// SA: 1 = A is single bf16 (Alo ignored; plane 1 zero-filled once).
template <int OM, int SA>
__global__ __launch_bounds__(256, 2) void k_gemm(const u16 *__restrict__ Ahi, const u16 *__restrict__ Alo,
                                                 const u16 *__restrict__ Bhi, const u16 *__restrict__ Blo,
                                                 const float *__restrict__ bias, void *__restrict__ out0,
                                                 int M, int N, int K) {
  __shared__ u16 sP[4][128 * 64];  // planes: Ahi, Alo, Bhi, Blo (16KB each)
  const int tid = threadIdx.x;
  const int w = tid >> 6, lane = tid & 63;
  const int la15 = lane & 15, la4 = lane >> 4;
  const int nbn = N >> 7;
  const int bm = blockIdx.x / nbn, bn = blockIdx.x % nbn;
  const u16 *src = (w == 0) ? Ahi : (w == 1) ? Alo : (w == 2) ? Bhi : Blo;
  const int rowbase = (w < 2) ? bm * 128 : bn * 128;
  char *lds = (char *)&sP[w][0];

  if (SA) {  // zero the Alo plane once; its MFMAs then contribute +0
    for (int i = tid; i < 2048; i += 256) ((unsigned long long *)&sP[1][0])[i] = 0ULL;
  }

  f32x4 acc[2][8] = {};
  for (int kb = 0; kb < K; kb += 64) {
    if (!(SA && w == 1)) {
#pragma unroll
      for (int i = 0; i < 16; ++i) {
        int s = i * 64 + lane;            // 16B slot id
        int row = s >> 3;                 // 8 slots per 128B row
        int k16 = (s & 7) ^ (row & 7);    // inverse of read swizzle
        dma16(src + (size_t)(rowbase + row) * K + kb + k16 * 8, lds + i * 1024);
      }
    }
    asm volatile("s_waitcnt vmcnt(0)" ::: "memory");
    __syncthreads();
#pragma unroll
    for (int ksl = 0; ksl < 2; ++ksl) {
      s16x8 ah[2], al[2];
#pragma unroll
      for (int rf = 0; rf < 2; ++rf) {
        int row = 32 * w + 16 * rf + la15;
        int slot = row * 8 + ((4 * ksl + la4) ^ (row & 7));
        ah[rf] = *(const s16x8 *)((const char *)&sP[0][0] + slot * 16);
        al[rf] = *(const s16x8 *)((const char *)&sP[1][0] + slot * 16);
      }
#pragma unroll
      for (int cf = 0; cf < 8; ++cf) {
        int col = 16 * cf + la15;
        int slot = col * 8 + ((4 * ksl + la4) ^ (col & 7));
        s16x8 bh = *(const s16x8 *)((const char *)&sP[2][0] + slot * 16);
        s16x8 bl = *(const s16x8 *)((const char *)&sP[3][0] + slot * 16);
#pragma unroll
        for (int rf = 0; rf < 2; ++rf) {
          acc[rf][cf] = mfma16(ah[rf], bh, acc[rf][cf]);
          acc[rf][cf] = mfma16(ah[rf], bl, acc[rf][cf]);
          acc[rf][cf] = mfma16(al[rf], bh, acc[rf][cf]);
        }
      }
    }
    __syncthreads();
  }
  // epilogue: D[r][c], r = 4*(lane>>4)+q (M), c = lane&15 (N)  [m89-verified]
#pragma unroll
  for (int rf = 0; rf < 2; ++rf) {
#pragma unroll
    for (int cf = 0; cf < 8; ++cf) {
      int c = bn * 128 + 16 * cf + la15;
      float bv = bias ? bias[c] : 0.f;
#pragma unroll
      for (int q = 0; q < 4; ++q) {
        int r = bm * 128 + 32 * w + 16 * rf + 4 * la4 + q;
        float v = acc[rf][cf][q] + bv;
        if (OM == 0) {
          ((u16 *)out0)[(size_t)r * N + c] = f2bf(v);
        } else {
          int b2 = r & 31, tt = r >> 5;  // A rows are m = t*32 + b
          ((float *)out0)[((size_t)b2 * SEQT + tt) * PDIM + c] = v;
        }
      }
    }
  }
}

// ---------------- pipelined 2-layer persistent LSTM recurrence (R11) ----------------
// R10 structure, but the h handshake is SENTINEL-BASED SPECULATION:
// h buffers are pre-filled with 0xFFFF (bf16 NaN, unreachable from f2bf of the
// finite gate outputs). Consumers load h[t-1] speculatively and retry until no
// sentinel — the load IS the poll. This removes flag store+drain+propagation
// and poll detection from every chain link. Producer h stores are
// fire-and-forget (write-once regions). zeff keeps flag0 (ring slots need a
// freshness tag; pre-satisfied in steady state -> ~free). flag1 survives only
// as L0's every-8-steps ring backpressure check. Ring depth 32 (8 MB).
__global__ __launch_bounds__(256, 1) void k_recur_pipe(
    const u16 *__restrict__ xz0, const float *__restrict__ Wh0, const float *__restrict__ Wh1,
    const u16 *__restrict__ Weff, const float *__restrict__ beff,
    u16 *h0h, u16 *h1h, u16 *zeffR, int *flags) {
  __shared__ u16 sW[32 * 1024];      // 64 KB: layer's Wh slice [zc][k] swizzled
  __shared__ u16 sE[32 * 1024];      // 64 KB: L0's Weff slice (unused by L1)
  __shared__ float zacc[4][32][33];  // per-wave K-partials (+1 col pad), 2-phase reuse
  __shared__ float sC[256];          // cell state c[32 rows][8 cols]
  const int tid = threadIdx.x;
  const int w = tid >> 6, lane = tid & 63;
  const int la15 = lane & 15, la4 = lane >> 4;
  const int wg = blockIdx.x;
  const int layer = wg >> 7;
  const int g = wg & 127;  // 8 h-cols: [8g, 8g+8)

  // stage weights (single bf16, swizzled), once per launch
  const float *Wh = layer ? Wh1 : Wh0;
  for (int i2 = tid; i2 < 32 * 1024; i2 += 256) {
    int zc = i2 & 31;
    int k = i2 >> 5;
    int gcol = (zc >> 3) * HDIM + 8 * g + (zc & 7);
    int boff = zc * 2048 + ((((k >> 3) ^ (zc & 7))) << 4) + (k & 7) * 2;
    *(u16 *)((char *)sW + boff) = f2bf(Wh[(size_t)k * G4H + gcol]);
    if (!layer) *(u16 *)((char *)sE + boff) = Weff[(size_t)k * G4H + gcol];
  }
  sC[tid] = 0.f;
  __syncthreads();

  const int r_g = tid >> 3, hc = tid & 7;  // gate coords: 32 rows x 8 cols
  const int ks0 = 8 * w;                   // wave's k-slice (256 k)

  if (!layer) {
    // ---------------- layer 0 (513 slots) ----------------
    for (int t = 0; t <= SEQT; ++t) {
      const bool last = (t == SEQT);
      float xzv[4] = {0.f, 0.f, 0.f, 0.f};
      if (!last) {
        const u16 *px = xz0 + ((size_t)r_g * SEQT + t) * G4H + 8 * g + hc;
#pragma unroll
        for (int gi = 0; gi < 4; ++gi) xzv[gi] = bf2f(px[(size_t)gi * HDIM]);
      }
      // rare ring backpressure: every 8 steps, require flag1 >= t-25
      // (ring 32: step u overwrites zeff[u-33], consumed by L1-step u-33 ->
      //  need flag1 >= u-32; checking for u in [t, t+8) -> bp = t-25).
      if (w == 0 && (t & 7) == 0 && t >= 26) {
        const int *f1 = flags + 128 + lane;
        const int bp = t - 25;
        for (long tries = 0;; ++tries) {
          int c = __hip_atomic_load(f1, __ATOMIC_RELAXED, __HIP_MEMORY_SCOPE_AGENT);
          int d = __hip_atomic_load(f1 + 64, __ATOMIC_RELAXED, __HIP_MEMORY_SCOPE_AGENT);
          if (__all(c >= bp && d >= bp)) break;
          if (tries > (1L << 22)) break;  // safety valve
          __builtin_amdgcn_s_sleep(1);
        }
      }
      f32x4 accE[2][2] = {};  // [rt][cf], survives to the reduce phase
      if (t > 0) {
        const u16 *pA = h0h + (size_t)(t - 1) * 32 * HDIM;
        // speculative load of h0[t-1] with sentinel validation (per wave)
        s16x8 aw0[8], aw1[8];
        for (long tries = 0;; ++tries) {
#pragma unroll
          for (int j8 = 0; j8 < 8; ++j8)
            aw0[j8] = ld128_dev(pA + (size_t)la15 * HDIM + 32 * (ks0 + j8) + 8 * la4);
#pragma unroll
          for (int j8 = 0; j8 < 8; ++j8)
            aw1[j8] = ld128_dev(pA + (size_t)(16 + la15) * HDIM + 32 * (ks0 + j8) + 8 * la4);
          asm volatile("s_waitcnt vmcnt(0)" ::: "memory");
          __builtin_amdgcn_sched_barrier(0);  // rule 18
          u32 bad = 0;
#pragma unroll
          for (int j8 = 0; j8 < 8; ++j8) bad |= sentq(aw0[j8]) | sentq(aw1[j8]);
          if (__all(bad == 0)) break;
          if (tries > (1L << 17)) break;  // safety valve
          __builtin_amdgcn_s_sleep(2);
        }
        {
          f32x4 acc0[2] = {};
#pragma unroll
          for (int j8 = 0; j8 < 8; ++j8) {
#pragma unroll
            for (int cf = 0; cf < 2; ++cf) {
              int zc = 16 * cf + la15;
              int sl = (4 * (ks0 + j8) + la4) ^ (zc & 7);
              int boff = zc * 2048 + (sl << 4);
              if (!last) acc0[cf] = mfma16(aw0[j8], *(const s16x8 *)((const char *)sW + boff), acc0[cf]);
              accE[0][cf] = mfma16(aw0[j8], *(const s16x8 *)((const char *)sE + boff), accE[0][cf]);
            }
          }
          if (!last) {
#pragma unroll
            for (int cf = 0; cf < 2; ++cf)
#pragma unroll
              for (int q = 0; q < 4; ++q) zacc[w][4 * la4 + q][16 * cf + la15] = acc0[cf][q];
          }
        }
        {
          f32x4 acc0[2] = {};
#pragma unroll
          for (int j8 = 0; j8 < 8; ++j8) {
#pragma unroll
            for (int cf = 0; cf < 2; ++cf) {
              int zc = 16 * cf + la15;
              int sl = (4 * (ks0 + j8) + la4) ^ (zc & 7);
              int boff = zc * 2048 + (sl << 4);
              if (!last) acc0[cf] = mfma16(aw1[j8], *(const s16x8 *)((const char *)sW + boff), acc0[cf]);
              accE[1][cf] = mfma16(aw1[j8], *(const s16x8 *)((const char *)sE + boff), accE[1][cf]);
            }
          }
          if (!last) {
#pragma unroll
            for (int cf = 0; cf < 2; ++cf)
#pragma unroll
              for (int q = 0; q < 4; ++q) zacc[w][16 + 4 * la4 + q][16 * cf + la15] = acc0[cf][q];
          }
        }
      }
      __syncthreads();  // zacc(acc0) ready for gates
      if (!last) {
        float z4[4];
#pragma unroll
        for (int gi = 0; gi < 4; ++gi) {
          float s = xzv[gi];
          if (t > 0) {
            int zc = gi * 8 + hc;
            s += zacc[0][r_g][zc] + zacc[1][r_g][zc] + zacc[2][r_g][zc] + zacc[3][r_g][zc];
          }
          z4[gi] = s;
        }
        float ig = fsig(z4[0]);
        float fg = fsig(z4[1]);
        float gg = ftanh(z4[2]);
        float og = fsig(z4[3]);
        float c = fg * sC[tid] + ig * gg;
        sC[tid] = c;
        float h = og * ftanh(c);
        // fire-and-forget: consumers detect via sentinel disappearance
        st16_dev(h0h + ((size_t)t * 32 + r_g) * HDIM + 8 * g + hc, f2bf(h));
      }
      __syncthreads();  // gates' zacc reads complete -> safe to overwrite
      if (t > 0) {
        // phase 2: zacc <- accE
#pragma unroll
        for (int rt = 0; rt < 2; ++rt)
#pragma unroll
          for (int cf = 0; cf < 2; ++cf)
#pragma unroll
            for (int q = 0; q < 4; ++q)
              zacc[w][16 * rt + 4 * la4 + q][16 * cf + la15] = accE[rt][cf][q];
      }
      __syncthreads();  // zacc(accE) ready
      if (t > 0) {
        // reduce across waves + pack 4 bf16 -> one coalesced 8B store
        float ze[4];
#pragma unroll
        for (int gi = 0; gi < 4; ++gi) {
          int zc = gi * 8 + hc;
          ze[gi] = zacc[0][r_g][zc] + zacc[1][r_g][zc] + zacc[2][r_g][zc] + zacc[3][r_g][zc];
        }
        i32x2 pk;
        pk[0] = (int)(((u32)f2bf(ze[1]) << 16) | (u32)f2bf(ze[0]));
        pk[1] = (int)(((u32)f2bf(ze[3]) << 16) | (u32)f2bf(ze[2]));
        st64_dev(zeffR + (((size_t)((t - 1) & 31) * 128 + g) << 10) + tid * 4, pk);
      }
      asm volatile("s_waitcnt vmcnt(0)" ::: "memory");  // zeff stores at L3 (per wave)
      __syncthreads();                                  // all waves drained
      if (tid == 0) st32_dev(flags + g, t + 1);         // flag0: zeff[t-1] complete
    }
  } else {
    // ---------------- layer 1 (512 slots, lag 2) ----------------
    float bef[4];
#pragma unroll
    for (int gi = 0; gi < 4; ++gi) bef[gi] = beff[gi * HDIM + 8 * g + hc];
    for (int t = 0; t < SEQT; ++t) {
      s16x8 aw0[8], aw1[8];
      const u16 *pA = h1h + ((t > 0) ? (size_t)(t - 1) * 32 * HDIM : 0);
      if (t > 0) {  // attempt 1 issued early, overlaps the flag0 poll
#pragma unroll
        for (int j8 = 0; j8 < 8; ++j8)
          aw0[j8] = ld128_dev(pA + (size_t)la15 * HDIM + 32 * (ks0 + j8) + 8 * la4);
#pragma unroll
        for (int j8 = 0; j8 < 8; ++j8)
          aw1[j8] = ld128_dev(pA + (size_t)(16 + la15) * HDIM + 32 * (ks0 + j8) + 8 * la4);
      }
      // per-wave flag0 poll (zeff[t] freshness tag); pre-satisfied in steady state
      {
        const int *f0 = flags + lane;
        const int need0 = t + 2;
        for (long tries = 0;; ++tries) {
          int a = __hip_atomic_load(f0, __ATOMIC_RELAXED, __HIP_MEMORY_SCOPE_AGENT);
          int b = __hip_atomic_load(f0 + 64, __ATOMIC_RELAXED, __HIP_MEMORY_SCOPE_AGENT);
          if (__all(a >= need0 && b >= need0)) break;
          if (tries > (1L << 22)) break;  // safety valve
          __builtin_amdgcn_s_sleep(1);
        }
      }
      i32x2 zpk = ld64_dev(zeffR + (((size_t)(t & 31) * 128 + g) << 10) + tid * 4);
      asm volatile("s_waitcnt vmcnt(0)" ::: "memory");
      __builtin_amdgcn_sched_barrier(0);  // rule 18
      // convert zeff to normal values NOW (spill-safe thereafter)
      float zv[4];
      zv[0] = bf2f((u16)((u32)zpk[0] & 0xffffu));
      zv[1] = bf2f((u16)((u32)zpk[0] >> 16));
      zv[2] = bf2f((u16)((u32)zpk[1] & 0xffffu));
      zv[3] = bf2f((u16)((u32)zpk[1] >> 16));
      if (t > 0) {
        // sentinel validation of h1[t-1]; retry loop reissues the 16 loads
        for (long tries = 0;; ++tries) {
          u32 bad = 0;
#pragma unroll
          for (int j8 = 0; j8 < 8; ++j8) bad |= sentq(aw0[j8]) | sentq(aw1[j8]);
          if (__all(bad == 0)) break;
          if (tries > (1L << 17)) break;  // safety valve
          __builtin_amdgcn_s_sleep(2);
#pragma unroll
          for (int j8 = 0; j8 < 8; ++j8)
            aw0[j8] = ld128_dev(pA + (size_t)la15 * HDIM + 32 * (ks0 + j8) + 8 * la4);
#pragma unroll
          for (int j8 = 0; j8 < 8; ++j8)
            aw1[j8] = ld128_dev(pA + (size_t)(16 + la15) * HDIM + 32 * (ks0 + j8) + 8 * la4);
          asm volatile("s_waitcnt vmcnt(0)" ::: "memory");
          __builtin_amdgcn_sched_barrier(0);
        }
        {
          f32x4 acc0[2] = {};
#pragma unroll
          for (int j8 = 0; j8 < 8; ++j8) {
#pragma unroll
            for (int cf = 0; cf < 2; ++cf) {
              int zc = 16 * cf + la15;
              int sl = (4 * (ks0 + j8) + la4) ^ (zc & 7);
              int boff = zc * 2048 + (sl << 4);
              acc0[cf] = mfma16(aw0[j8], *(const s16x8 *)((const char *)sW + boff), acc0[cf]);
            }
          }
#pragma unroll
          for (int cf = 0; cf < 2; ++cf)
#pragma unroll
            for (int q = 0; q < 4; ++q) zacc[w][4 * la4 + q][16 * cf + la15] = acc0[cf][q];
        }
        {
          f32x4 acc0[2] = {};
#pragma unroll
          for (int j8 = 0; j8 < 8; ++j8) {
#pragma unroll
            for (int cf = 0; cf < 2; ++cf) {
              int zc = 16 * cf + la15;
              int sl = (4 * (ks0 + j8) + la4) ^ (zc & 7);
              int boff = zc * 2048 + (sl << 4);
              acc0[cf] = mfma16(aw1[j8], *(const s16x8 *)((const char *)sW + boff), acc0[cf]);
            }
          }
#pragma unroll
          for (int cf = 0; cf < 2; ++cf)
#pragma unroll
            for (int q = 0; q < 4; ++q) zacc[w][16 + 4 * la4 + q][16 * cf + la15] = acc0[cf][q];
        }
      }
      __syncthreads();  // zacc ready; also: all waves' zeff/h reads retired
      if (tid == 0) st32_dev(flags + 128 + g, t + 1);  // flag1: ring slot consumed
      {
        float z4[4];
#pragma unroll
        for (int gi = 0; gi < 4; ++gi) {
          float s = bef[gi] + zv[gi];
          if (t > 0) {
            int zc = gi * 8 + hc;
            s += zacc[0][r_g][zc] + zacc[1][r_g][zc] + zacc[2][r_g][zc] + zacc[3][r_g][zc];
          }
          z4[gi] = s;
        }
        float ig = fsig(z4[0]);
        float fg = fsig(z4[1]);
        float gg = ftanh(z4[2]);
        float og = fsig(z4[3]);
        float c = fg * sC[tid] + ig * gg;
        sC[tid] = c;
        float h = og * ftanh(c);
        st16_dev(h1h + ((size_t)t * 32 + r_g) * HDIM + 8 * g + hc, f2bf(h));  // fire-and-forget
      }
      __syncthreads();  // zacc protect for next iteration
    }
  }
}

// ---------------- host launcher ----------------
extern "C" void kernel_launch(void *const *d_in, const int *in_sizes, int n_in,
                              void *d_out, int out_size, void *d_ws, size_t ws_size,
                              hipStream_t stream) {
  const int *tokens = (const int *)d_in[0];
  const float *embed = (const float *)d_in[1];
  const float *Wx0 = (const float *)d_in[2];
  const float *Wh0 = (const float *)d_in[3];
  const float *b0 = (const float *)d_in[4];
  const float *Wfc0 = (const float *)d_in[5];
  const float *bfc0 = (const float *)d_in[6];
  const float *Wx1 = (const float *)d_in[7];
  const float *Wh1 = (const float *)d_in[8];
  const float *b1 = (const float *)d_in[9];
  const float *Wfc1 = (const float *)d_in[10];
  const float *bfc1 = (const float *)d_in[11];

  constexpr size_t NEED = 255856640;  // ~244 MiB (unchanged from validated R1)
  if (ws_size < NEED) {
    fprintf(stderr, "RNNLM kernel: ws too small (%zu < %zu)\n", ws_size, NEED);
    return;
  }
  char *ws = (char *)d_ws;
  u16 *xz0 = (u16 *)(ws + 0);           // [16384][4096] bf16, rows m=b*T+t
  u16 *h0h = (u16 *)(ws + 134217728);   // h0 hist [512][32][1024] bf16 (32 MB)
  u16 *h1h = (u16 *)(ws + 167772160);   // h1 hist (32 MB)
  u16 *x0hi = (u16 *)(ws + 201326592);  // 16 MB, dead after xz0 GEMM
  u16 *x0lo = (u16 *)(ws + 218103808);  // 16 MB, dead after xz0 GEMM
  // carved into the x0 region AFTER the xz0 GEMM (stream-ordered):
  u16 *Weff = (u16 *)(ws + 201326592);      // [1024][4096] bf16 (8 MB)
  u16 *Wfc0hi = (u16 *)(ws + 209715200);    // [1024][512] (1 MB)
  u16 *Wfc0lo = (u16 *)(ws + 210763776);    // 1 MB
  u16 *WfcT1hi = (u16 *)(ws + 211812352);   // [512][1024] (1 MB)
  u16 *WfcT1lo = (u16 *)(ws + 212860928);   // 1 MB
  float *beff = (float *)(ws + 213909504);  // [4096] f32 (16 KB)
  int *flags = (int *)(ws + 213925888);     // [256] (1 KB)
  // zeffR ring [32][128][1024] bf16 = 8 MB, in the dead x0lo region.
  u16 *zeffR = (u16 *)(ws + 218103808);
  // own regions (live until their consumer GEMMs):
  u16 *WxT0hi = (u16 *)(ws + 234881024);  // [4096][512] (4 MB)
  u16 *WxT0lo = (u16 *)(ws + 239075328);
  u16 *WxT1hi = (u16 *)(ws + 243269632);  // [4096][512] (4 MB)
  u16 *WxT1lo = (u16 *)(ws + 247463936);  // ends 251658240

  // sentinel-fill the h buffers (h0h+h1h are contiguous 64 MB) — EVERY launch
  // (harness does not re-poison d_ws between graph replays).
  (void)hipMemsetAsync(h0h, 0xFF, 67108864, stream);

  // prepack (regions disjoint from x0)
  k_packT<<<dim3(G4H / 32, DEMB / 32), dim3(32, 8), 0, stream>>>(Wx0, WxT0hi, WxT0lo, DEMB, G4H);
  k_packT<<<dim3(G4H / 32, DEMB / 32), dim3(32, 8), 0, stream>>>(Wx1, WxT1hi, WxT1lo, DEMB, G4H);
  // x0 = embed[tokens] hi/lo
  k_gather_pack<<<4096, 256, 0, stream>>>(tokens, embed, x0hi, x0lo);
  // xz0 = x0 @ Wx0 + b0 -> bf16 (rows m = b*T + t)
  k_gemm<0, 0><<<dim3(128 * 32), 256, 0, stream>>>(x0hi, x0lo, WxT0hi, WxT0lo, b0, xz0,
                                                   16384, G4H, DEMB);
  // x0 now dead: build fused layer-1 input path in its place
  k_split<<<2048, 256, 0, stream>>>(Wfc0, Wfc0hi, Wfc0lo, HDIM * PDIM);
  k_packT<<<dim3(PDIM / 32, HDIM / 32), dim3(32, 8), 0, stream>>>(Wfc1, WfcT1hi, WfcT1lo, HDIM, PDIM);
  k_beff<<<16, 256, 0, stream>>>(bfc0, Wx1, b1, beff);
  (void)hipMemsetAsync(flags, 0, 256 * sizeof(int), stream);
  // Weff = Wfc0 @ Wx1 -> bf16 [1024][4096]  (A=Wfc0 hi/lo, B=WxT1 hi/lo)
  k_gemm<0, 0><<<dim3(8 * 32), 256, 0, stream>>>(Wfc0hi, Wfc0lo, WxT1hi, WxT1lo, nullptr, Weff,
                                                 1024, G4H, PDIM);
  // sentinel-speculation pipelined both-layer recurrence (one coop dispatch)
  {
    const u16 *a0 = xz0; const float *a1 = Wh0; const float *a2 = Wh1;
    const u16 *a3 = Weff; const float *a4 = beff;
    u16 *a5 = h0h; u16 *a6 = h1h; u16 *a7 = zeffR; int *a8 = flags;
    void *args[] = {&a0, &a1, &a2, &a3, &a4, &a5, &a6, &a7, &a8};
    hipError_t e = hipLaunchCooperativeKernel((void *)k_recur_pipe, dim3(256), dim3(256), args, 0, stream);
    if (e != hipSuccess) fprintf(stderr, "coop launch failed: %d\n", (int)e);
  }
  // out = h1 @ Wfc1 + bfc1 -> f32 scattered to (B,T,P)  (A single bf16)
  k_gemm<2, 1><<<dim3(128 * 4), 256, 0, stream>>>(h1h, h1h, WfcT1hi, WfcT1lo, bfc1, d_out,
                                                  16384, PDIM, HDIM);
}